// Round 1
// baseline (1731.056 us; speedup 1.0000x reference)
//
#include <hip/hip_runtime.h>
#include <cmath>

#define N_CLASS 128
#define N_SUP   32
#define N_QRY   128
#define D_IN    2048
#define Z_DIM   1024
#define NPROTO  256
#define N_S     (N_CLASS * N_SUP)   // 4096
#define N_Q     (N_CLASS * N_QRY)   // 16384
#define N_ROWS  (N_S + N_Q)         // 20480

// ---------------- Kernel A: z = [xs; xq] @ W (fp32 tiled GEMM) ----------------
// 128x128 tile, BK=16, 256 threads, 8x8 per thread.
#define BM 128
#define BN 128
#define BK 16

__global__ __launch_bounds__(256) void gemm_xw(
    const float* __restrict__ xs, const float* __restrict__ xq,
    const float* __restrict__ W, float* __restrict__ z)
{
    __shared__ float sA[BK][BM + 4];   // +4 pad: keeps float4 alignment, breaks stride
    __shared__ float sB[BK][BN];
    const int tid  = threadIdx.x;
    const int row0 = blockIdx.y * BM;
    const int col0 = blockIdx.x * BN;
    const int tx = tid & 15;
    const int ty = tid >> 4;

    // A loader: 128 rows x 16 k = 2048 floats = 512 float4; 2 per thread
    const int fa0 = tid, fa1 = tid + 256;
    const int am0 = fa0 >> 2, ak0 = (fa0 & 3) << 2;
    const int am1 = fa1 >> 2, ak1 = (fa1 & 3) << 2;
    const int r0 = row0 + am0, r1 = row0 + am1;
    const float* pa0 = (r0 < N_S) ? (xs + (size_t)r0 * D_IN) : (xq + (size_t)(r0 - N_S) * D_IN);
    const float* pa1 = (r1 < N_S) ? (xs + (size_t)r1 * D_IN) : (xq + (size_t)(r1 - N_S) * D_IN);

    // B loader: 16 k x 128 cols = 512 float4; 2 per thread
    const int bk0 = tid >> 5,        bc0 = (tid & 31) << 2;
    const int bk1 = (tid + 256) >> 5, bc1 = (tid & 31) << 2;

    float acc[8][8];
#pragma unroll
    for (int i = 0; i < 8; ++i)
#pragma unroll
        for (int j = 0; j < 8; ++j) acc[i][j] = 0.f;

    for (int k0 = 0; k0 < D_IN; k0 += BK) {
        float4 a0 = *(const float4*)(pa0 + k0 + ak0);
        float4 a1 = *(const float4*)(pa1 + k0 + ak1);
        float4 b0 = *(const float4*)(W + (size_t)(k0 + bk0) * Z_DIM + col0 + bc0);
        float4 b1 = *(const float4*)(W + (size_t)(k0 + bk1) * Z_DIM + col0 + bc1);
        sA[ak0 + 0][am0] = a0.x; sA[ak0 + 1][am0] = a0.y;
        sA[ak0 + 2][am0] = a0.z; sA[ak0 + 3][am0] = a0.w;
        sA[ak1 + 0][am1] = a1.x; sA[ak1 + 1][am1] = a1.y;
        sA[ak1 + 2][am1] = a1.z; sA[ak1 + 3][am1] = a1.w;
        *(float4*)&sB[bk0][bc0] = b0;
        *(float4*)&sB[bk1][bc1] = b1;
        __syncthreads();
#pragma unroll
        for (int kk = 0; kk < BK; ++kk) {
            float4 av0 = *(const float4*)&sA[kk][ty * 8];
            float4 av1 = *(const float4*)&sA[kk][ty * 8 + 4];
            float4 bv0 = *(const float4*)&sB[kk][tx * 8];
            float4 bv1 = *(const float4*)&sB[kk][tx * 8 + 4];
            float a[8] = {av0.x, av0.y, av0.z, av0.w, av1.x, av1.y, av1.z, av1.w};
            float b[8] = {bv0.x, bv0.y, bv0.z, bv0.w, bv1.x, bv1.y, bv1.z, bv1.w};
#pragma unroll
            for (int i = 0; i < 8; ++i)
#pragma unroll
                for (int j = 0; j < 8; ++j)
                    acc[i][j] = fmaf(a[i], b[j], acc[i][j]);
        }
        __syncthreads();
    }
#pragma unroll
    for (int i = 0; i < 8; ++i) {
        float* zr = z + (size_t)(row0 + ty * 8 + i) * Z_DIM + col0 + tx * 8;
        float4 v0 = {acc[i][0], acc[i][1], acc[i][2], acc[i][3]};
        float4 v1 = {acc[i][4], acc[i][5], acc[i][6], acc[i][7]};
        *(float4*)(zr + 0) = v0;
        *(float4*)(zr + 4) = v1;
    }
}

// ---------------- Kernel B: per-class assignment + centroids + proto norms ----
__global__ __launch_bounds__(256) void centroids_kernel(
    const float* __restrict__ z, float* __restrict__ protos, float* __restrict__ pnorm)
{
    const int c = blockIdx.x;
    const float* zc = z + (size_t)c * N_SUP * Z_DIM;
    __shared__ int s_assign[N_SUP];
    __shared__ float red0[4], red1[4];
    const int lane = threadIdx.x & 63;
    const int wave = threadIdx.x >> 6;

    // assignment: argmin over K=2 inits (zs[c][0], zs[c][1]); ties -> 0
    for (int s = wave; s < N_SUP; s += 4) {
        const float* zr = zc + (size_t)s * Z_DIM;
        float d0 = 0.f, d1 = 0.f;
        for (int i = lane; i < Z_DIM; i += 64) {
            float v  = zr[i];
            float t0 = v - zc[i];
            float t1 = v - zc[Z_DIM + i];
            d0 = fmaf(t0, t0, d0);
            d1 = fmaf(t1, t1, d1);
        }
        for (int off = 32; off; off >>= 1) {
            d0 += __shfl_down(d0, off);
            d1 += __shfl_down(d1, off);
        }
        if (lane == 0) s_assign[s] = (d1 < d0) ? 1 : 0;
    }
    __syncthreads();

    int cnt1 = 0;
    for (int s = 0; s < N_SUP; ++s) cnt1 += s_assign[s];
    const int cnt0 = N_SUP - cnt1;

    float n0 = 0.f, n1 = 0.f;
    for (int d = threadIdx.x; d < Z_DIM; d += 256) {
        float s0 = 0.f, s1 = 0.f;
        for (int s = 0; s < N_SUP; ++s) {
            float v = zc[(size_t)s * Z_DIM + d];
            if (s_assign[s]) s1 += v; else s0 += v;
        }
        float c0 = (cnt0 > 0) ? (s0 / (float)cnt0) : zc[d];
        float c1 = (cnt1 > 0) ? (s1 / (float)cnt1) : zc[Z_DIM + d];
        protos[(size_t)(2 * c)     * Z_DIM + d] = c0;
        protos[(size_t)(2 * c + 1) * Z_DIM + d] = c1;
        n0 = fmaf(c0, c0, n0);
        n1 = fmaf(c1, c1, n1);
    }
    for (int off = 32; off; off >>= 1) {
        n0 += __shfl_down(n0, off);
        n1 += __shfl_down(n1, off);
    }
    if (lane == 0) { red0[wave] = n0; red1[wave] = n1; }
    __syncthreads();
    if (threadIdx.x == 0) {
        pnorm[2 * c]     = red0[0] + red0[1] + red0[2] + red0[3];
        pnorm[2 * c + 1] = red1[0] + red1[1] + red1[2] + red1[3];
    }
}

// ---------------- qnorm: ||zq_row||^2 ----------------
__global__ __launch_bounds__(256) void qnorm_kernel(
    const float* __restrict__ zq, float* __restrict__ qnorm)
{
    const int q = blockIdx.x * 4 + (threadIdx.x >> 6);
    const int lane = threadIdx.x & 63;
    const float* row = zq + (size_t)q * Z_DIM;
    float s = 0.f;
    for (int i = lane; i < Z_DIM; i += 64) { float v = row[i]; s = fmaf(v, v, s); }
    for (int off = 32; off; off >>= 1) s += __shfl_down(s, off);
    if (lane == 0) qnorm[q] = s;
}

// ---------------- Kernel C: dists[q][c] = min_k max(||q||^2+||p||^2-2<q,p>, 0) --
// Block: 32 queries x all 256 protos. 256 threads as (ty 0..7 queries, tx 0..31 protos).
#define CBK 16
__global__ __launch_bounds__(256) void dist_kernel(
    const float* __restrict__ zq, const float* __restrict__ protos,
    const float* __restrict__ pnorm, const float* __restrict__ qnorm,
    float* __restrict__ dists)
{
    __shared__ float sP[CBK][NPROTO];
    __shared__ float sQ[CBK][36];
    const int tid = threadIdx.x;
    const int q0  = blockIdx.x * 32;
    const int tx  = tid & 31;
    const int ty  = tid >> 5;

    float acc[4][8];
#pragma unroll
    for (int i = 0; i < 4; ++i)
#pragma unroll
        for (int j = 0; j < 8; ++j) acc[i][j] = 0.f;

    const int qr = tid >> 2, qk = (tid & 3) << 2;    // used when tid < 128

    for (int k0 = 0; k0 < Z_DIM; k0 += CBK) {
        float4 qv = {0, 0, 0, 0};
        if (tid < 128) qv = *(const float4*)(zq + (size_t)(q0 + qr) * Z_DIM + k0 + qk);
        float4 pv[4];
#pragma unroll
        for (int r = 0; r < 4; ++r) {
            int f = tid + 256 * r;
            int pp = f >> 2, pk = (f & 3) << 2;
            pv[r] = *(const float4*)(protos + (size_t)pp * Z_DIM + k0 + pk);
        }
        if (tid < 128) {
            sQ[qk + 0][qr] = qv.x; sQ[qk + 1][qr] = qv.y;
            sQ[qk + 2][qr] = qv.z; sQ[qk + 3][qr] = qv.w;
        }
#pragma unroll
        for (int r = 0; r < 4; ++r) {
            int f = tid + 256 * r;
            int pp = f >> 2, pk = (f & 3) << 2;
            sP[pk + 0][pp] = pv[r].x; sP[pk + 1][pp] = pv[r].y;
            sP[pk + 2][pp] = pv[r].z; sP[pk + 3][pp] = pv[r].w;
        }
        __syncthreads();
#pragma unroll
        for (int kk = 0; kk < CBK; ++kk) {
            float4 qv4 = *(const float4*)&sQ[kk][ty * 4];
            float4 p0  = *(const float4*)&sP[kk][tx * 8];
            float4 p1  = *(const float4*)&sP[kk][tx * 8 + 4];
            float qa[4] = {qv4.x, qv4.y, qv4.z, qv4.w};
            float pb[8] = {p0.x, p0.y, p0.z, p0.w, p1.x, p1.y, p1.z, p1.w};
#pragma unroll
            for (int i = 0; i < 4; ++i)
#pragma unroll
                for (int j = 0; j < 8; ++j)
                    acc[i][j] = fmaf(qa[i], pb[j], acc[i][j]);
        }
        __syncthreads();
    }

    float pnr[8];
#pragma unroll
    for (int t = 0; t < 8; ++t) pnr[t] = pnorm[tx * 8 + t];

#pragma unroll
    for (int i = 0; i < 4; ++i) {
        const int q = q0 + ty * 4 + i;
        const float qn = qnorm[q];
        float d[4];
#pragma unroll
        for (int j = 0; j < 4; ++j) {
            float d0 = qn + pnr[2 * j]     - 2.f * acc[i][2 * j];
            float d1 = qn + pnr[2 * j + 1] - 2.f * acc[i][2 * j + 1];
            d0 = fmaxf(d0, 0.f);
            d1 = fmaxf(d1, 0.f);
            d[j] = fminf(d0, d1);
        }
        float4 dv = {d[0], d[1], d[2], d[3]};
        *(float4*)&dists[(size_t)q * N_CLASS + tx * 4] = dv;
    }
}

// ---------------- Kernel D: per-query sum / argmax / own-class log term -------
__global__ __launch_bounds__(256) void reduce_kernel(
    const float* __restrict__ dists, float* __restrict__ accum)
{
    const int q = blockIdx.x * 4 + (threadIdx.x >> 6);
    const int lane = threadIdx.x & 63;
    const float* dr = dists + (size_t)q * N_CLASS;
    const float va = dr[lane];
    const float vb = dr[lane + 64];
    float sum = va + vb;
    float bv; int bi;
    if (vb > va) { bv = vb; bi = lane + 64; } else { bv = va; bi = lane; }
    for (int off = 32; off; off >>= 1) {
        sum += __shfl_down(sum, off);
        float ov = __shfl_down(bv, off);
        int   oi = __shfl_down(bi, off);
        if (ov > bv || (ov == bv && oi < bi)) { bv = ov; bi = oi; }
    }
    if (lane == 0) {
        const int c = q >> 7;              // own class = q / 128
        const float own = dr[c];
        atomicAdd(&accum[0], logf(own / sum));
        atomicAdd(&accum[1], (bi == c) ? 1.f : 0.f);
    }
}

__global__ void finalize_kernel(const float* __restrict__ accum, float* __restrict__ out)
{
    if (threadIdx.x == 0) {
        out[0] = -accum[0] / (float)N_Q;
        out[1] =  accum[1] / (float)N_Q;
    }
}

// ---------------- launch ----------------
extern "C" void kernel_launch(void* const* d_in, const int* in_sizes, int n_in,
                              void* d_out, int out_size, void* d_ws, size_t ws_size,
                              hipStream_t stream)
{
    (void)in_sizes; (void)n_in; (void)out_size; (void)ws_size;
    const float* xs = (const float*)d_in[0];
    const float* xq = (const float*)d_in[1];
    const float* W  = (const float*)d_in[2];
    float* out = (float*)d_out;

    char* ws = (char*)d_ws;
    float* z      = (float*)(ws);                         // 20480*1024*4 = 83,886,080
    float* protos = (float*)(ws + 83886080ull);           // 256*1024*4   =  1,048,576
    float* pnorm  = (float*)(ws + 84934656ull);           // 256*4
    float* qnorm  = (float*)(ws + 84935680ull);           // 16384*4
    float* dists  = (float*)(ws + 85001216ull);           // 16384*128*4  =  8,388,608
    float* accum  = (float*)(ws + 93389824ull);           // 2*4

    dim3 gA(Z_DIM / BN, N_ROWS / BM);                     // (8, 160)
    gemm_xw<<<gA, 256, 0, stream>>>(xs, xq, W, z);

    const float* zq = z + (size_t)N_S * Z_DIM;
    qnorm_kernel<<<N_Q / 4, 256, 0, stream>>>(zq, qnorm);
    centroids_kernel<<<N_CLASS, 256, 0, stream>>>(z, protos, pnorm);
    dist_kernel<<<N_Q / 32, 256, 0, stream>>>(zq, protos, pnorm, qnorm, dists);

    hipMemsetAsync(accum, 0, 2 * sizeof(float), stream);
    reduce_kernel<<<N_Q / 4, 256, 0, stream>>>(dists, accum);
    finalize_kernel<<<1, 64, 0, stream>>>(accum, out);
}

// Round 2
// 1006.292 us; speedup vs baseline: 1.7202x; 1.7202x over previous
//
#include <hip/hip_runtime.h>
#include <cmath>

#define N_CLASS 128
#define N_SUP   32
#define N_QRY   128
#define D_IN    2048
#define Z_DIM   1024
#define NPROTO  256
#define N_S     (N_CLASS * N_SUP)   // 4096
#define N_Q     (N_CLASS * N_QRY)   // 16384
#define N_ROWS  (N_S + N_Q)         // 20480

typedef __attribute__((ext_vector_type(4))) float f32x4;
typedef __attribute__((ext_vector_type(8))) short bf16x8;

__device__ __forceinline__ unsigned short f2bf(float f) {
    unsigned u = __float_as_uint(f);
    u += 0x7fffu + ((u >> 16) & 1u);   // RNE
    return (unsigned short)(u >> 16);
}

__device__ __forceinline__ void load_lds16(const unsigned short* g, unsigned short* l) {
    __builtin_amdgcn_global_load_lds(
        (const __attribute__((address_space(1))) unsigned int*)g,
        (__attribute__((address_space(3))) unsigned int*)l, 16, 0, 0);
}

// ---------------- cast fp32 -> bf16 (4 floats / thread) ----------------
__global__ __launch_bounds__(256) void cast_bf16(
    const float* __restrict__ in, unsigned short* __restrict__ out)
{
    const int i = (blockIdx.x * 256 + threadIdx.x) * 4;
    float4 v = *(const float4*)(in + i);
    ushort4 o;
    o.x = f2bf(v.x); o.y = f2bf(v.y); o.z = f2bf(v.z); o.w = f2bf(v.w);
    *(ushort4*)(out + i) = o;
}

// ---------------- W (K x N fp32) -> Wt (N x K bf16), tiled transpose ----------
__global__ __launch_bounds__(256) void wt_kernel(
    const float* __restrict__ W, unsigned short* __restrict__ wt)
{
    __shared__ unsigned short t[64][65];
    const int n0 = blockIdx.x * 64;
    const int k0 = blockIdx.y * 64;
#pragma unroll
    for (int e = 0; e < 16; ++e) {
        int idx = e * 256 + threadIdx.x;
        int r = idx >> 6, c = idx & 63;            // r: k, c: n
        t[c][r] = f2bf(W[(size_t)(k0 + r) * Z_DIM + n0 + c]);
    }
    __syncthreads();
#pragma unroll
    for (int e = 0; e < 16; ++e) {
        int idx = e * 256 + threadIdx.x;
        int r = idx >> 6, c = idx & 63;            // r: n, c: k
        wt[(size_t)(n0 + r) * D_IN + k0 + c] = t[r][c];
    }
}

// ---------------- bf16 MFMA GEMM: z[20480x1024] = xb[20480x2048] @ WtT ---------
// 128x128 tile, BK=32, 256 threads (4 waves 2x2), 16x16x32 MFMA, 4x4 tiles/wave.
#define GBM 128
#define GBN 128
#define GBK 32

__global__ __launch_bounds__(256) void gemm_mfma(
    const unsigned short* __restrict__ xb,   // 20480 x 2048 (row-major, bf16)
    const unsigned short* __restrict__ wt,   // 1024 x 2048 (N x K, bf16)
    float* __restrict__ z)                   // 20480 x 1024 fp32
{
    __shared__ unsigned short sA[GBM * GBK]; // 128 rows x 32 k, row-major
    __shared__ unsigned short sB[GBN * GBK]; // 128 n-rows x 32 k, row-major
    const int tid  = threadIdx.x;
    const int m0   = blockIdx.y * GBM;
    const int n0   = blockIdx.x * GBN;
    const int lane = tid & 63;
    const int wave = tid >> 6;
    const int wm   = (wave >> 1) * 64;
    const int wn   = (wave & 1) * 64;

    // staging: thread t stages 16B chunks t and t+256 of each 8192B tile
    // chunk f: row = f>>2, in-row offset = (f&3)*8 bf16
    const int f0 = tid, f1 = tid + 256;
    const unsigned short* ga0 = xb + (size_t)(m0 + (f0 >> 2)) * D_IN + ((f0 & 3) << 3);
    const unsigned short* ga1 = xb + (size_t)(m0 + (f1 >> 2)) * D_IN + ((f1 & 3) << 3);
    const unsigned short* gb0 = wt + (size_t)(n0 + (f0 >> 2)) * D_IN + ((f0 & 3) << 3);
    const unsigned short* gb1 = wt + (size_t)(n0 + (f1 >> 2)) * D_IN + ((f1 & 3) << 3);
    unsigned short* la0 = &sA[f0 * 8];
    unsigned short* la1 = &sA[f1 * 8];
    unsigned short* lb0 = &sB[f0 * 8];
    unsigned short* lb1 = &sB[f1 * 8];

    f32x4 acc[4][4];
#pragma unroll
    for (int i = 0; i < 4; ++i)
#pragma unroll
        for (int j = 0; j < 4; ++j) acc[i][j] = (f32x4){0.f, 0.f, 0.f, 0.f};

    const int ra = wm + (lane & 15);          // A fragment row base
    const int rb = wn + (lane & 15);          // B fragment n-row base
    const int ko = (lane >> 4) * 8;           // k offset within tile

    for (int k0 = 0; k0 < D_IN; k0 += GBK) {
        load_lds16(ga0 + k0, la0);
        load_lds16(ga1 + k0, la1);
        load_lds16(gb0 + k0, lb0);
        load_lds16(gb1 + k0, lb1);
        __syncthreads();

        bf16x8 af[4], bfr[4];
#pragma unroll
        for (int i = 0; i < 4; ++i)
            af[i] = *(const bf16x8*)&sA[(ra + i * 16) * GBK + ko];
#pragma unroll
        for (int j = 0; j < 4; ++j)
            bfr[j] = *(const bf16x8*)&sB[(rb + j * 16) * GBK + ko];
#pragma unroll
        for (int i = 0; i < 4; ++i)
#pragma unroll
            for (int j = 0; j < 4; ++j)
                acc[i][j] = __builtin_amdgcn_mfma_f32_16x16x32_bf16(
                    af[i], bfr[j], acc[i][j], 0, 0, 0);
        __syncthreads();
    }

    // C/D layout: col = lane&15, row = (lane>>4)*4 + reg
#pragma unroll
    for (int i = 0; i < 4; ++i) {
#pragma unroll
        for (int j = 0; j < 4; ++j) {
            const int m = m0 + wm + i * 16 + (lane >> 4) * 4;
            const int n = n0 + wn + j * 16 + (lane & 15);
#pragma unroll
            for (int r = 0; r < 4; ++r)
                z[(size_t)(m + r) * Z_DIM + n] = acc[i][j][r];
        }
    }
}

// ---------------- per-class assignment + centroids + proto norms ----
__global__ __launch_bounds__(256) void centroids_kernel(
    const float* __restrict__ z, float* __restrict__ protos, float* __restrict__ pnorm)
{
    const int c = blockIdx.x;
    const float* zc = z + (size_t)c * N_SUP * Z_DIM;
    __shared__ int s_assign[N_SUP];
    __shared__ float red0[4], red1[4];
    const int lane = threadIdx.x & 63;
    const int wave = threadIdx.x >> 6;

    for (int s = wave; s < N_SUP; s += 4) {
        const float* zr = zc + (size_t)s * Z_DIM;
        float d0 = 0.f, d1 = 0.f;
        for (int i = lane; i < Z_DIM; i += 64) {
            float v  = zr[i];
            float t0 = v - zc[i];
            float t1 = v - zc[Z_DIM + i];
            d0 = fmaf(t0, t0, d0);
            d1 = fmaf(t1, t1, d1);
        }
        for (int off = 32; off; off >>= 1) {
            d0 += __shfl_down(d0, off);
            d1 += __shfl_down(d1, off);
        }
        if (lane == 0) s_assign[s] = (d1 < d0) ? 1 : 0;
    }
    __syncthreads();

    int cnt1 = 0;
    for (int s = 0; s < N_SUP; ++s) cnt1 += s_assign[s];
    const int cnt0 = N_SUP - cnt1;

    float n0 = 0.f, n1 = 0.f;
    for (int d = threadIdx.x; d < Z_DIM; d += 256) {
        float s0 = 0.f, s1 = 0.f;
        for (int s = 0; s < N_SUP; ++s) {
            float v = zc[(size_t)s * Z_DIM + d];
            if (s_assign[s]) s1 += v; else s0 += v;
        }
        float c0 = (cnt0 > 0) ? (s0 / (float)cnt0) : zc[d];
        float c1 = (cnt1 > 0) ? (s1 / (float)cnt1) : zc[Z_DIM + d];
        protos[(size_t)(2 * c)     * Z_DIM + d] = c0;
        protos[(size_t)(2 * c + 1) * Z_DIM + d] = c1;
        n0 = fmaf(c0, c0, n0);
        n1 = fmaf(c1, c1, n1);
    }
    for (int off = 32; off; off >>= 1) {
        n0 += __shfl_down(n0, off);
        n1 += __shfl_down(n1, off);
    }
    if (lane == 0) { red0[wave] = n0; red1[wave] = n1; }
    __syncthreads();
    if (threadIdx.x == 0) {
        pnorm[2 * c]     = red0[0] + red0[1] + red0[2] + red0[3];
        pnorm[2 * c + 1] = red1[0] + red1[1] + red1[2] + red1[3];
    }
}

// ---------------- qnorm ----------------
__global__ __launch_bounds__(256) void qnorm_kernel(
    const float* __restrict__ zq, float* __restrict__ qnorm)
{
    const int q = blockIdx.x * 4 + (threadIdx.x >> 6);
    const int lane = threadIdx.x & 63;
    const float* row = zq + (size_t)q * Z_DIM;
    float s = 0.f;
    for (int i = lane; i < Z_DIM; i += 64) { float v = row[i]; s = fmaf(v, v, s); }
    for (int off = 32; off; off >>= 1) s += __shfl_down(s, off);
    if (lane == 0) qnorm[q] = s;
}

// ---------------- dists[q][c] = min_k max(||q||^2+||p||^2-2<q,p>, 0) --
#define CBK 16
__global__ __launch_bounds__(256) void dist_kernel(
    const float* __restrict__ zq, const float* __restrict__ protos,
    const float* __restrict__ pnorm, const float* __restrict__ qnorm,
    float* __restrict__ dists)
{
    __shared__ float sP[CBK][NPROTO];
    __shared__ float sQ[CBK][36];
    const int tid = threadIdx.x;
    const int q0  = blockIdx.x * 32;
    const int tx  = tid & 31;
    const int ty  = tid >> 5;

    float acc[4][8];
#pragma unroll
    for (int i = 0; i < 4; ++i)
#pragma unroll
        for (int j = 0; j < 8; ++j) acc[i][j] = 0.f;

    const int qr = tid >> 2, qk = (tid & 3) << 2;

    for (int k0 = 0; k0 < Z_DIM; k0 += CBK) {
        float4 qv = {0, 0, 0, 0};
        if (tid < 128) qv = *(const float4*)(zq + (size_t)(q0 + qr) * Z_DIM + k0 + qk);
        float4 pv[4];
#pragma unroll
        for (int r = 0; r < 4; ++r) {
            int f = tid + 256 * r;
            int pp = f >> 2, pk = (f & 3) << 2;
            pv[r] = *(const float4*)(protos + (size_t)pp * Z_DIM + k0 + pk);
        }
        if (tid < 128) {
            sQ[qk + 0][qr] = qv.x; sQ[qk + 1][qr] = qv.y;
            sQ[qk + 2][qr] = qv.z; sQ[qk + 3][qr] = qv.w;
        }
#pragma unroll
        for (int r = 0; r < 4; ++r) {
            int f = tid + 256 * r;
            int pp = f >> 2, pk = (f & 3) << 2;
            sP[pk + 0][pp] = pv[r].x; sP[pk + 1][pp] = pv[r].y;
            sP[pk + 2][pp] = pv[r].z; sP[pk + 3][pp] = pv[r].w;
        }
        __syncthreads();
#pragma unroll
        for (int kk = 0; kk < CBK; ++kk) {
            float4 qv4 = *(const float4*)&sQ[kk][ty * 4];
            float4 p0  = *(const float4*)&sP[kk][tx * 8];
            float4 p1  = *(const float4*)&sP[kk][tx * 8 + 4];
            float qa[4] = {qv4.x, qv4.y, qv4.z, qv4.w};
            float pb[8] = {p0.x, p0.y, p0.z, p0.w, p1.x, p1.y, p1.z, p1.w};
#pragma unroll
            for (int i = 0; i < 4; ++i)
#pragma unroll
                for (int j = 0; j < 8; ++j)
                    acc[i][j] = fmaf(qa[i], pb[j], acc[i][j]);
        }
        __syncthreads();
    }

    float pnr[8];
#pragma unroll
    for (int t = 0; t < 8; ++t) pnr[t] = pnorm[tx * 8 + t];

#pragma unroll
    for (int i = 0; i < 4; ++i) {
        const int q = q0 + ty * 4 + i;
        const float qn = qnorm[q];
        float d[4];
#pragma unroll
        for (int j = 0; j < 4; ++j) {
            float d0 = qn + pnr[2 * j]     - 2.f * acc[i][2 * j];
            float d1 = qn + pnr[2 * j + 1] - 2.f * acc[i][2 * j + 1];
            d0 = fmaxf(d0, 0.f);
            d1 = fmaxf(d1, 0.f);
            d[j] = fminf(d0, d1);
        }
        float4 dv = {d[0], d[1], d[2], d[3]};
        *(float4*)&dists[(size_t)q * N_CLASS + tx * 4] = dv;
    }
}

// ---------------- per-query reduce ----------------
__global__ __launch_bounds__(256) void reduce_kernel(
    const float* __restrict__ dists, float* __restrict__ accum)
{
    const int q = blockIdx.x * 4 + (threadIdx.x >> 6);
    const int lane = threadIdx.x & 63;
    const float* dr = dists + (size_t)q * N_CLASS;
    const float va = dr[lane];
    const float vb = dr[lane + 64];
    float sum = va + vb;
    float bv; int bi;
    if (vb > va) { bv = vb; bi = lane + 64; } else { bv = va; bi = lane; }
    for (int off = 32; off; off >>= 1) {
        sum += __shfl_down(sum, off);
        float ov = __shfl_down(bv, off);
        int   oi = __shfl_down(bi, off);
        if (ov > bv || (ov == bv && oi < bi)) { bv = ov; bi = oi; }
    }
    if (lane == 0) {
        const int c = q >> 7;
        const float own = dr[c];
        atomicAdd(&accum[0], logf(own / sum));
        atomicAdd(&accum[1], (bi == c) ? 1.f : 0.f);
    }
}

__global__ void finalize_kernel(const float* __restrict__ accum, float* __restrict__ out)
{
    if (threadIdx.x == 0) {
        out[0] = -accum[0] / (float)N_Q;
        out[1] =  accum[1] / (float)N_Q;
    }
}

// ---------------- launch ----------------
extern "C" void kernel_launch(void* const* d_in, const int* in_sizes, int n_in,
                              void* d_out, int out_size, void* d_ws, size_t ws_size,
                              hipStream_t stream)
{
    (void)in_sizes; (void)n_in; (void)out_size; (void)ws_size;
    const float* xs = (const float*)d_in[0];
    const float* xq = (const float*)d_in[1];
    const float* W  = (const float*)d_in[2];
    float* out = (float*)d_out;

    char* ws = (char*)d_ws;
    float*          z      = (float*)(ws);                       //  83,886,080 B
    unsigned short* xb     = (unsigned short*)(ws + 83886080ull);//  83,886,080 B
    unsigned short* wt     = (unsigned short*)(ws + 167772160ull);//  4,194,304 B
    float*          protos = (float*)(ws + 171966464ull);        //   1,048,576 B
    float*          pnorm  = (float*)(ws + 173015040ull);        //       1,024 B
    float*          qnorm  = (float*)(ws + 173016064ull);        //      65,536 B
    float*          dists  = (float*)(ws + 173081600ull);        //   8,388,608 B
    float*          accum  = (float*)(ws + 181470208ull);        //           8 B

    // bf16 conversions
    cast_bf16<<<N_S * D_IN / 1024, 256, 0, stream>>>(xs, xb);
    cast_bf16<<<N_Q * D_IN / 1024, 256, 0, stream>>>(xq, xb + (size_t)N_S * D_IN);
    wt_kernel<<<dim3(Z_DIM / 64, D_IN / 64), 256, 0, stream>>>(W, wt);

    // main GEMM (bf16 MFMA)
    dim3 gA(Z_DIM / GBN, N_ROWS / GBM);   // (8, 160)
    gemm_mfma<<<gA, 256, 0, stream>>>(xb, wt, z);

    const float* zq = z + (size_t)N_S * Z_DIM;
    qnorm_kernel<<<N_Q / 4, 256, 0, stream>>>(zq, qnorm);
    centroids_kernel<<<N_CLASS, 256, 0, stream>>>(z, protos, pnorm);
    dist_kernel<<<N_Q / 32, 256, 0, stream>>>(zq, protos, pnorm, qnorm, dists);

    hipMemsetAsync(accum, 0, 2 * sizeof(float), stream);
    reduce_kernel<<<N_Q / 4, 256, 0, stream>>>(dists, accum);
    finalize_kernel<<<1, 64, 0, stream>>>(accum, out);
}

// Round 3
// 590.467 us; speedup vs baseline: 2.9317x; 1.7042x over previous
//
#include <hip/hip_runtime.h>
#include <cmath>

#define N_CLASS 128
#define N_SUP   32
#define N_QRY   128
#define D_IN    2048
#define Z_DIM   1024
#define NPROTO  256
#define N_S     (N_CLASS * N_SUP)   // 4096
#define N_Q     (N_CLASS * N_QRY)   // 16384
#define N_ROWS  (N_S + N_Q)         // 20480
#define N_RBLK  (N_Q / 4)           // 4096 reduce blocks

typedef __attribute__((ext_vector_type(4))) float f32x4;
typedef __attribute__((ext_vector_type(8))) short bf16x8;

__device__ __forceinline__ unsigned short f2bf(float f) {
    unsigned u = __float_as_uint(f);
    u += 0x7fffu + ((u >> 16) & 1u);   // RNE
    return (unsigned short)(u >> 16);
}

__device__ __forceinline__ void load_lds16(const unsigned short* g, unsigned short* l) {
    __builtin_amdgcn_global_load_lds(
        (const __attribute__((address_space(1))) unsigned int*)g,
        (__attribute__((address_space(3))) unsigned int*)l, 16, 0, 0);
}

// ---------------- cast fp32 -> bf16 (4 floats / thread) ----------------
__global__ __launch_bounds__(256) void cast_bf16(
    const float* __restrict__ in, unsigned short* __restrict__ out)
{
    const int i = (blockIdx.x * 256 + threadIdx.x) * 4;
    float4 v = *(const float4*)(in + i);
    ushort4 o;
    o.x = f2bf(v.x); o.y = f2bf(v.y); o.z = f2bf(v.z); o.w = f2bf(v.w);
    *(ushort4*)(out + i) = o;
}

// ---------------- W (K x N fp32) -> Wt (N x K bf16), tiled transpose ----------
__global__ __launch_bounds__(256) void wt_kernel(
    const float* __restrict__ W, unsigned short* __restrict__ wt)
{
    __shared__ unsigned short t[64][65];
    const int n0 = blockIdx.x * 64;
    const int k0 = blockIdx.y * 64;
#pragma unroll
    for (int e = 0; e < 16; ++e) {
        int idx = e * 256 + threadIdx.x;
        int r = idx >> 6, c = idx & 63;            // r: k, c: n
        t[c][r] = f2bf(W[(size_t)(k0 + r) * Z_DIM + n0 + c]);
    }
    __syncthreads();
#pragma unroll
    for (int e = 0; e < 16; ++e) {
        int idx = e * 256 + threadIdx.x;
        int r = idx >> 6, c = idx & 63;            // r: n, c: k
        wt[(size_t)(n0 + r) * D_IN + k0 + c] = t[r][c];
    }
}

// ---------------- bf16 MFMA GEMM: z[20480x1024] = xb @ WtT ---------
#define GBM 128
#define GBN 128
#define GBK 32

__global__ __launch_bounds__(256) void gemm_mfma(
    const unsigned short* __restrict__ xb,   // 20480 x 2048 (row-major, bf16)
    const unsigned short* __restrict__ wt,   // 1024 x 2048 (N x K, bf16)
    float* __restrict__ z)                   // 20480 x 1024 fp32
{
    __shared__ unsigned short sA[GBM * GBK];
    __shared__ unsigned short sB[GBN * GBK];
    const int tid  = threadIdx.x;
    const int m0   = blockIdx.y * GBM;
    const int n0   = blockIdx.x * GBN;
    const int lane = tid & 63;
    const int wave = tid >> 6;
    const int wm   = (wave >> 1) * 64;
    const int wn   = (wave & 1) * 64;

    const int f0 = tid, f1 = tid + 256;
    const unsigned short* ga0 = xb + (size_t)(m0 + (f0 >> 2)) * D_IN + ((f0 & 3) << 3);
    const unsigned short* ga1 = xb + (size_t)(m0 + (f1 >> 2)) * D_IN + ((f1 & 3) << 3);
    const unsigned short* gb0 = wt + (size_t)(n0 + (f0 >> 2)) * D_IN + ((f0 & 3) << 3);
    const unsigned short* gb1 = wt + (size_t)(n0 + (f1 >> 2)) * D_IN + ((f1 & 3) << 3);
    unsigned short* la0 = &sA[f0 * 8];
    unsigned short* la1 = &sA[f1 * 8];
    unsigned short* lb0 = &sB[f0 * 8];
    unsigned short* lb1 = &sB[f1 * 8];

    f32x4 acc[4][4];
#pragma unroll
    for (int i = 0; i < 4; ++i)
#pragma unroll
        for (int j = 0; j < 4; ++j) acc[i][j] = (f32x4){0.f, 0.f, 0.f, 0.f};

    const int ra = wm + (lane & 15);
    const int rb = wn + (lane & 15);
    const int ko = (lane >> 4) * 8;

    for (int k0 = 0; k0 < D_IN; k0 += GBK) {
        load_lds16(ga0 + k0, la0);
        load_lds16(ga1 + k0, la1);
        load_lds16(gb0 + k0, lb0);
        load_lds16(gb1 + k0, lb1);
        __syncthreads();

        bf16x8 af[4], bfr[4];
#pragma unroll
        for (int i = 0; i < 4; ++i)
            af[i] = *(const bf16x8*)&sA[(ra + i * 16) * GBK + ko];
#pragma unroll
        for (int j = 0; j < 4; ++j)
            bfr[j] = *(const bf16x8*)&sB[(rb + j * 16) * GBK + ko];
#pragma unroll
        for (int i = 0; i < 4; ++i)
#pragma unroll
            for (int j = 0; j < 4; ++j)
                acc[i][j] = __builtin_amdgcn_mfma_f32_16x16x32_bf16(
                    af[i], bfr[j], acc[i][j], 0, 0, 0);
        __syncthreads();
    }

#pragma unroll
    for (int i = 0; i < 4; ++i) {
#pragma unroll
        for (int j = 0; j < 4; ++j) {
            const int m = m0 + wm + i * 16 + (lane >> 4) * 4;
            const int n = n0 + wn + j * 16 + (lane & 15);
#pragma unroll
            for (int r = 0; r < 4; ++r)
                z[(size_t)(m + r) * Z_DIM + n] = acc[i][j][r];
        }
    }
}

// ---------------- per-class assignment + centroids + proto norms ----
__global__ __launch_bounds__(256) void centroids_kernel(
    const float* __restrict__ z, float* __restrict__ protos, float* __restrict__ pnorm)
{
    const int c = blockIdx.x;
    const float* zc = z + (size_t)c * N_SUP * Z_DIM;
    __shared__ int s_assign[N_SUP];
    __shared__ float red0[4], red1[4];
    const int lane = threadIdx.x & 63;
    const int wave = threadIdx.x >> 6;

    for (int s = wave; s < N_SUP; s += 4) {
        const float* zr = zc + (size_t)s * Z_DIM;
        float d0 = 0.f, d1 = 0.f;
        for (int i = lane; i < Z_DIM; i += 64) {
            float v  = zr[i];
            float t0 = v - zc[i];
            float t1 = v - zc[Z_DIM + i];
            d0 = fmaf(t0, t0, d0);
            d1 = fmaf(t1, t1, d1);
        }
        for (int off = 32; off; off >>= 1) {
            d0 += __shfl_down(d0, off);
            d1 += __shfl_down(d1, off);
        }
        if (lane == 0) s_assign[s] = (d1 < d0) ? 1 : 0;
    }
    __syncthreads();

    int cnt1 = 0;
    for (int s = 0; s < N_SUP; ++s) cnt1 += s_assign[s];
    const int cnt0 = N_SUP - cnt1;

    float n0 = 0.f, n1 = 0.f;
    for (int d = threadIdx.x; d < Z_DIM; d += 256) {
        float s0 = 0.f, s1 = 0.f;
        for (int s = 0; s < N_SUP; ++s) {
            float v = zc[(size_t)s * Z_DIM + d];
            if (s_assign[s]) s1 += v; else s0 += v;
        }
        float c0 = (cnt0 > 0) ? (s0 / (float)cnt0) : zc[d];
        float c1 = (cnt1 > 0) ? (s1 / (float)cnt1) : zc[Z_DIM + d];
        protos[(size_t)(2 * c)     * Z_DIM + d] = c0;
        protos[(size_t)(2 * c + 1) * Z_DIM + d] = c1;
        n0 = fmaf(c0, c0, n0);
        n1 = fmaf(c1, c1, n1);
    }
    for (int off = 32; off; off >>= 1) {
        n0 += __shfl_down(n0, off);
        n1 += __shfl_down(n1, off);
    }
    if (lane == 0) { red0[wave] = n0; red1[wave] = n1; }
    __syncthreads();
    if (threadIdx.x == 0) {
        pnorm[2 * c]     = red0[0] + red0[1] + red0[2] + red0[3];
        pnorm[2 * c + 1] = red1[0] + red1[1] + red1[2] + red1[3];
    }
}

// ---------------- qnorm ----------------
__global__ __launch_bounds__(256) void qnorm_kernel(
    const float* __restrict__ zq, float* __restrict__ qnorm)
{
    const int q = blockIdx.x * 4 + (threadIdx.x >> 6);
    const int lane = threadIdx.x & 63;
    const float* row = zq + (size_t)q * Z_DIM;
    float s = 0.f;
    for (int i = lane; i < Z_DIM; i += 64) { float v = row[i]; s = fmaf(v, v, s); }
    for (int off = 32; off; off >>= 1) s += __shfl_down(s, off);
    if (lane == 0) qnorm[q] = s;
}

// ---------------- dists[q][c] = min_k max(||q||^2+||p||^2-2<q,p>, 0) --
#define CBK 16
__global__ __launch_bounds__(256) void dist_kernel(
    const float* __restrict__ zq, const float* __restrict__ protos,
    const float* __restrict__ pnorm, const float* __restrict__ qnorm,
    float* __restrict__ dists)
{
    __shared__ float sP[CBK][NPROTO];
    __shared__ float sQ[CBK][36];
    const int tid = threadIdx.x;
    const int q0  = blockIdx.x * 32;
    const int tx  = tid & 31;
    const int ty  = tid >> 5;

    float acc[4][8];
#pragma unroll
    for (int i = 0; i < 4; ++i)
#pragma unroll
        for (int j = 0; j < 8; ++j) acc[i][j] = 0.f;

    const int qr = tid >> 2, qk = (tid & 3) << 2;

    for (int k0 = 0; k0 < Z_DIM; k0 += CBK) {
        float4 qv = {0, 0, 0, 0};
        if (tid < 128) qv = *(const float4*)(zq + (size_t)(q0 + qr) * Z_DIM + k0 + qk);
        float4 pv[4];
#pragma unroll
        for (int r = 0; r < 4; ++r) {
            int f = tid + 256 * r;
            int pp = f >> 2, pk = (f & 3) << 2;
            pv[r] = *(const float4*)(protos + (size_t)pp * Z_DIM + k0 + pk);
        }
        if (tid < 128) {
            sQ[qk + 0][qr] = qv.x; sQ[qk + 1][qr] = qv.y;
            sQ[qk + 2][qr] = qv.z; sQ[qk + 3][qr] = qv.w;
        }
#pragma unroll
        for (int r = 0; r < 4; ++r) {
            int f = tid + 256 * r;
            int pp = f >> 2, pk = (f & 3) << 2;
            sP[pk + 0][pp] = pv[r].x; sP[pk + 1][pp] = pv[r].y;
            sP[pk + 2][pp] = pv[r].z; sP[pk + 3][pp] = pv[r].w;
        }
        __syncthreads();
#pragma unroll
        for (int kk = 0; kk < CBK; ++kk) {
            float4 qv4 = *(const float4*)&sQ[kk][ty * 4];
            float4 p0  = *(const float4*)&sP[kk][tx * 8];
            float4 p1  = *(const float4*)&sP[kk][tx * 8 + 4];
            float qa[4] = {qv4.x, qv4.y, qv4.z, qv4.w};
            float pb[8] = {p0.x, p0.y, p0.z, p0.w, p1.x, p1.y, p1.z, p1.w};
#pragma unroll
            for (int i = 0; i < 4; ++i)
#pragma unroll
                for (int j = 0; j < 8; ++j)
                    acc[i][j] = fmaf(qa[i], pb[j], acc[i][j]);
        }
        __syncthreads();
    }

    float pnr[8];
#pragma unroll
    for (int t = 0; t < 8; ++t) pnr[t] = pnorm[tx * 8 + t];

#pragma unroll
    for (int i = 0; i < 4; ++i) {
        const int q = q0 + ty * 4 + i;
        const float qn = qnorm[q];
        float d[4];
#pragma unroll
        for (int j = 0; j < 4; ++j) {
            float d0 = qn + pnr[2 * j]     - 2.f * acc[i][2 * j];
            float d1 = qn + pnr[2 * j + 1] - 2.f * acc[i][2 * j + 1];
            d0 = fmaxf(d0, 0.f);
            d1 = fmaxf(d1, 0.f);
            d[j] = fminf(d0, d1);
        }
        float4 dv = {d[0], d[1], d[2], d[3]};
        *(float4*)&dists[(size_t)q * N_CLASS + tx * 4] = dv;
    }
}

// ---------------- per-query reduce -> per-block partial (no atomics) ----------
__global__ __launch_bounds__(256) void reduce_kernel(
    const float* __restrict__ dists, float2* __restrict__ partial)
{
    const int wave = threadIdx.x >> 6;
    const int q = blockIdx.x * 4 + wave;
    const int lane = threadIdx.x & 63;
    const float* dr = dists + (size_t)q * N_CLASS;
    __shared__ float2 s_part[4];

    const float va = dr[lane];
    const float vb = dr[lane + 64];
    float sum = va + vb;
    float bv; int bi;
    if (vb > va) { bv = vb; bi = lane + 64; } else { bv = va; bi = lane; }
    for (int off = 32; off; off >>= 1) {
        sum += __shfl_down(sum, off);
        float ov = __shfl_down(bv, off);
        int   oi = __shfl_down(bi, off);
        if (ov > bv || (ov == bv && oi < bi)) { bv = ov; bi = oi; }
    }
    if (lane == 0) {
        const int c = q >> 7;
        const float own = dr[c];
        s_part[wave] = make_float2(logf(own / sum), (bi == c) ? 1.f : 0.f);
    }
    __syncthreads();
    if (threadIdx.x == 0) {
        float2 a = s_part[0], b = s_part[1], c2 = s_part[2], d = s_part[3];
        partial[blockIdx.x] = make_float2(a.x + b.x + c2.x + d.x,
                                          a.y + b.y + c2.y + d.y);
    }
}

// ---------------- final reduce over 4096 partials (single block) --------------
__global__ __launch_bounds__(1024) void finalize_kernel(
    const float2* __restrict__ partial, float* __restrict__ out)
{
    __shared__ float sl[16], sa[16];
    const int tid = threadIdx.x;
    float l = 0.f, a = 0.f;
#pragma unroll
    for (int i = 0; i < 4; ++i) {
        float2 p = partial[tid * 4 + i];
        l += p.x; a += p.y;
    }
    for (int off = 32; off; off >>= 1) {
        l += __shfl_down(l, off);
        a += __shfl_down(a, off);
    }
    const int lane = tid & 63, wave = tid >> 6;
    if (lane == 0) { sl[wave] = l; sa[wave] = a; }
    __syncthreads();
    if (tid == 0) {
        float L = 0.f, A = 0.f;
#pragma unroll
        for (int w = 0; w < 16; ++w) { L += sl[w]; A += sa[w]; }
        out[0] = -L / (float)N_Q;
        out[1] =  A / (float)N_Q;
    }
}

// ---------------- launch ----------------
extern "C" void kernel_launch(void* const* d_in, const int* in_sizes, int n_in,
                              void* d_out, int out_size, void* d_ws, size_t ws_size,
                              hipStream_t stream)
{
    (void)in_sizes; (void)n_in; (void)out_size; (void)ws_size;
    const float* xs = (const float*)d_in[0];
    const float* xq = (const float*)d_in[1];
    const float* W  = (const float*)d_in[2];
    float* out = (float*)d_out;

    char* ws = (char*)d_ws;
    float*          z      = (float*)(ws);                        //  83,886,080 B
    unsigned short* xb     = (unsigned short*)(ws + 83886080ull); //  83,886,080 B
    unsigned short* wt     = (unsigned short*)(ws + 167772160ull);//   4,194,304 B
    float*          protos = (float*)(ws + 171966464ull);         //   1,048,576 B
    float*          pnorm  = (float*)(ws + 173015040ull);         //       1,024 B
    float*          qnorm  = (float*)(ws + 173016064ull);         //      65,536 B
    float*          dists  = (float*)(ws + 173081600ull);         //   8,388,608 B
    float2*         partial= (float2*)(ws + 181470208ull);        //      32,768 B

    cast_bf16<<<N_S * D_IN / 1024, 256, 0, stream>>>(xs, xb);
    cast_bf16<<<N_Q * D_IN / 1024, 256, 0, stream>>>(xq, xb + (size_t)N_S * D_IN);
    wt_kernel<<<dim3(Z_DIM / 64, D_IN / 64), 256, 0, stream>>>(W, wt);

    dim3 gA(Z_DIM / GBN, N_ROWS / GBM);   // (8, 160)
    gemm_mfma<<<gA, 256, 0, stream>>>(xb, wt, z);

    const float* zq = z + (size_t)N_S * Z_DIM;
    qnorm_kernel<<<N_Q / 4, 256, 0, stream>>>(zq, qnorm);
    centroids_kernel<<<N_CLASS, 256, 0, stream>>>(z, protos, pnorm);
    dist_kernel<<<N_Q / 32, 256, 0, stream>>>(zq, protos, pnorm, qnorm, dists);

    reduce_kernel<<<N_RBLK, 256, 0, stream>>>(dists, partial);
    finalize_kernel<<<1, 1024, 0, stream>>>(partial, out);
}

// Round 4
// 473.295 us; speedup vs baseline: 3.6575x; 1.2476x over previous
//
#include <hip/hip_runtime.h>
#include <cmath>

#define N_CLASS 128
#define N_SUP   32
#define N_QRY   128
#define D_IN    2048
#define Z_DIM   1024
#define NPROTO  256
#define N_S     (N_CLASS * N_SUP)   // 4096
#define N_Q     (N_CLASS * N_QRY)   // 16384
#define N_ROWS  (N_S + N_Q)         // 20480
#define N_RBLK  (N_Q / 4)           // 4096 reduce blocks

typedef __attribute__((ext_vector_type(4))) float f32x4;
typedef __attribute__((ext_vector_type(8))) short bf16x8;
typedef _Float16 f16x8 __attribute__((ext_vector_type(8)));
typedef _Float16 f16x4 __attribute__((ext_vector_type(4)));

__device__ __forceinline__ unsigned short f2bf(float f) {
    unsigned u = __float_as_uint(f);
    u += 0x7fffu + ((u >> 16) & 1u);   // RNE
    return (unsigned short)(u >> 16);
}

__device__ __forceinline__ void load_lds16(const void* g, void* l) {
    __builtin_amdgcn_global_load_lds(
        (const __attribute__((address_space(1))) unsigned int*)g,
        (__attribute__((address_space(3))) unsigned int*)l, 16, 0, 0);
}

// ---------------- cast fp32 -> bf16 (4 floats / thread) ----------------
__global__ __launch_bounds__(256) void cast_bf16(
    const float* __restrict__ in, unsigned short* __restrict__ out)
{
    const int i = (blockIdx.x * 256 + threadIdx.x) * 4;
    float4 v = *(const float4*)(in + i);
    ushort4 o;
    o.x = f2bf(v.x); o.y = f2bf(v.y); o.z = f2bf(v.z); o.w = f2bf(v.w);
    *(ushort4*)(out + i) = o;
}

// ---------------- W (K x N fp32) -> Wt (N x K bf16), tiled transpose ----------
__global__ __launch_bounds__(256) void wt_kernel(
    const float* __restrict__ W, unsigned short* __restrict__ wt)
{
    __shared__ unsigned short t[64][65];
    const int n0 = blockIdx.x * 64;
    const int k0 = blockIdx.y * 64;
#pragma unroll
    for (int e = 0; e < 16; ++e) {
        int idx = e * 256 + threadIdx.x;
        int r = idx >> 6, c = idx & 63;            // r: k, c: n
        t[c][r] = f2bf(W[(size_t)(k0 + r) * Z_DIM + n0 + c]);
    }
    __syncthreads();
#pragma unroll
    for (int e = 0; e < 16; ++e) {
        int idx = e * 256 + threadIdx.x;
        int r = idx >> 6, c = idx & 63;            // r: n, c: k
        wt[(size_t)(n0 + r) * D_IN + k0 + c] = t[r][c];
    }
}

// ---------------- bf16 MFMA GEMM: z[20480x1024] = xb @ WtT ---------
#define GBM 128
#define GBN 128
#define GBK 32

__global__ __launch_bounds__(256) void gemm_mfma(
    const unsigned short* __restrict__ xb,   // 20480 x 2048 (row-major, bf16)
    const unsigned short* __restrict__ wt,   // 1024 x 2048 (N x K, bf16)
    float* __restrict__ z)                   // 20480 x 1024 fp32
{
    __shared__ unsigned short sA[GBM * GBK];
    __shared__ unsigned short sB[GBN * GBK];
    const int tid  = threadIdx.x;
    const int m0   = blockIdx.y * GBM;
    const int n0   = blockIdx.x * GBN;
    const int lane = tid & 63;
    const int wave = tid >> 6;
    const int wm   = (wave >> 1) * 64;
    const int wn   = (wave & 1) * 64;

    const int f0 = tid, f1 = tid + 256;
    const unsigned short* ga0 = xb + (size_t)(m0 + (f0 >> 2)) * D_IN + ((f0 & 3) << 3);
    const unsigned short* ga1 = xb + (size_t)(m0 + (f1 >> 2)) * D_IN + ((f1 & 3) << 3);
    const unsigned short* gb0 = wt + (size_t)(n0 + (f0 >> 2)) * D_IN + ((f0 & 3) << 3);
    const unsigned short* gb1 = wt + (size_t)(n0 + (f1 >> 2)) * D_IN + ((f1 & 3) << 3);
    unsigned short* la0 = &sA[f0 * 8];
    unsigned short* la1 = &sA[f1 * 8];
    unsigned short* lb0 = &sB[f0 * 8];
    unsigned short* lb1 = &sB[f1 * 8];

    f32x4 acc[4][4];
#pragma unroll
    for (int i = 0; i < 4; ++i)
#pragma unroll
        for (int j = 0; j < 4; ++j) acc[i][j] = (f32x4){0.f, 0.f, 0.f, 0.f};

    const int ra = wm + (lane & 15);
    const int rb = wn + (lane & 15);
    const int ko = (lane >> 4) * 8;

    for (int k0 = 0; k0 < D_IN; k0 += GBK) {
        load_lds16(ga0 + k0, la0);
        load_lds16(ga1 + k0, la1);
        load_lds16(gb0 + k0, lb0);
        load_lds16(gb1 + k0, lb1);
        __syncthreads();

        bf16x8 af[4], bfr[4];
#pragma unroll
        for (int i = 0; i < 4; ++i)
            af[i] = *(const bf16x8*)&sA[(ra + i * 16) * GBK + ko];
#pragma unroll
        for (int j = 0; j < 4; ++j)
            bfr[j] = *(const bf16x8*)&sB[(rb + j * 16) * GBK + ko];
#pragma unroll
        for (int i = 0; i < 4; ++i)
#pragma unroll
            for (int j = 0; j < 4; ++j)
                acc[i][j] = __builtin_amdgcn_mfma_f32_16x16x32_bf16(
                    af[i], bfr[j], acc[i][j], 0, 0, 0);
        __syncthreads();
    }

#pragma unroll
    for (int i = 0; i < 4; ++i) {
#pragma unroll
        for (int j = 0; j < 4; ++j) {
            const int m = m0 + wm + i * 16 + (lane >> 4) * 4;
            const int n = n0 + wn + j * 16 + (lane & 15);
#pragma unroll
            for (int r = 0; r < 4; ++r)
                z[(size_t)(m + r) * Z_DIM + n] = acc[i][j][r];
        }
    }
}

// ---- per-class assignment + centroids (f16 out) + fp32 proto norms ----
__global__ __launch_bounds__(256) void centroids_kernel(
    const float* __restrict__ z, _Float16* __restrict__ ph, float* __restrict__ pnorm)
{
    const int c = blockIdx.x;
    const float* zc = z + (size_t)c * N_SUP * Z_DIM;
    __shared__ int s_assign[N_SUP];
    __shared__ float red0[4], red1[4];
    const int lane = threadIdx.x & 63;
    const int wave = threadIdx.x >> 6;

    for (int s = wave; s < N_SUP; s += 4) {
        const float* zr = zc + (size_t)s * Z_DIM;
        float d0 = 0.f, d1 = 0.f;
        for (int i = lane; i < Z_DIM; i += 64) {
            float v  = zr[i];
            float t0 = v - zc[i];
            float t1 = v - zc[Z_DIM + i];
            d0 = fmaf(t0, t0, d0);
            d1 = fmaf(t1, t1, d1);
        }
        for (int off = 32; off; off >>= 1) {
            d0 += __shfl_down(d0, off);
            d1 += __shfl_down(d1, off);
        }
        if (lane == 0) s_assign[s] = (d1 < d0) ? 1 : 0;
    }
    __syncthreads();

    int cnt1 = 0;
    for (int s = 0; s < N_SUP; ++s) cnt1 += s_assign[s];
    const int cnt0 = N_SUP - cnt1;

    float n0 = 0.f, n1 = 0.f;
    for (int d = threadIdx.x; d < Z_DIM; d += 256) {
        float s0 = 0.f, s1 = 0.f;
        for (int s = 0; s < N_SUP; ++s) {
            float v = zc[(size_t)s * Z_DIM + d];
            if (s_assign[s]) s1 += v; else s0 += v;
        }
        float c0 = (cnt0 > 0) ? (s0 / (float)cnt0) : zc[d];
        float c1 = (cnt1 > 0) ? (s1 / (float)cnt1) : zc[Z_DIM + d];
        ph[(size_t)(2 * c)     * Z_DIM + d] = (_Float16)c0;
        ph[(size_t)(2 * c + 1) * Z_DIM + d] = (_Float16)c1;
        n0 = fmaf(c0, c0, n0);
        n1 = fmaf(c1, c1, n1);
    }
    for (int off = 32; off; off >>= 1) {
        n0 += __shfl_down(n0, off);
        n1 += __shfl_down(n1, off);
    }
    if (lane == 0) { red0[wave] = n0; red1[wave] = n1; }
    __syncthreads();
    if (threadIdx.x == 0) {
        pnorm[2 * c]     = red0[0] + red0[1] + red0[2] + red0[3];
        pnorm[2 * c + 1] = red1[0] + red1[1] + red1[2] + red1[3];
    }
}

// ---------------- qnorm + f16 cast of zq (one wave per row) ----------------
__global__ __launch_bounds__(256) void qnorm_cast(
    const float* __restrict__ zq, float* __restrict__ qnorm, _Float16* __restrict__ zqh)
{
    const int wave = threadIdx.x >> 6, lane = threadIdx.x & 63;
    const int q = blockIdx.x * 4 + wave;
    const float* row = zq + (size_t)q * Z_DIM;
    _Float16* orow = zqh + (size_t)q * Z_DIM;
    float s = 0.f;
#pragma unroll
    for (int it = 0; it < 4; ++it) {
        const int idx = (it * 64 + lane) * 4;
        float4 v = *(const float4*)(row + idx);
        s = fmaf(v.x, v.x, fmaf(v.y, v.y, fmaf(v.z, v.z, fmaf(v.w, v.w, s))));
        f16x4 o = {(_Float16)v.x, (_Float16)v.y, (_Float16)v.z, (_Float16)v.w};
        *(f16x4*)(orow + idx) = o;
    }
    for (int off = 32; off; off >>= 1) s += __shfl_down(s, off);
    if (lane == 0) qnorm[q] = s;
}

// ---- dist via f16 MFMA: S=zq@protos^T; dists[q][c]=min_k max(qn+pn-2S,0) ----
#define DBM 128
#define DBN 64
#define DBK 32
__global__ __launch_bounds__(256) void dist_mfma(
    const _Float16* __restrict__ zqh,   // 16384 x 1024
    const _Float16* __restrict__ ph,    // 256 x 1024 (N x K)
    const float* __restrict__ pnorm, const float* __restrict__ qnorm,
    float* __restrict__ dists)          // 16384 x 128
{
    __shared__ _Float16 sA[DBM * DBK];  // 8 KB
    __shared__ _Float16 sB[DBN * DBK];  // 4 KB
    const int tid  = threadIdx.x;
    const int m0   = blockIdx.y * DBM;
    const int n0   = blockIdx.x * DBN;
    const int lane = tid & 63;
    const int wave = tid >> 6;
    const int wm   = (wave >> 1) * 64;
    const int wn   = (wave & 1) * 32;

    // A: 512 chunks of 16B (2/thread); B: 256 chunks (1/thread)
    const int f0 = tid, f1 = tid + 256;
    const _Float16* ga0 = zqh + (size_t)(m0 + (f0 >> 2)) * Z_DIM + ((f0 & 3) << 3);
    const _Float16* ga1 = zqh + (size_t)(m0 + (f1 >> 2)) * Z_DIM + ((f1 & 3) << 3);
    const _Float16* gb0 = ph  + (size_t)(n0 + (tid >> 2)) * Z_DIM + ((tid & 3) << 3);
    _Float16* la0 = &sA[f0 * 8];
    _Float16* la1 = &sA[f1 * 8];
    _Float16* lb0 = &sB[tid * 8];

    f32x4 acc[4][2];
#pragma unroll
    for (int i = 0; i < 4; ++i)
#pragma unroll
        for (int j = 0; j < 2; ++j) acc[i][j] = (f32x4){0.f, 0.f, 0.f, 0.f};

    const int ra = wm + (lane & 15);
    const int rb = wn + (lane & 15);
    const int ko = (lane >> 4) * 8;

    for (int k0 = 0; k0 < Z_DIM; k0 += DBK) {
        load_lds16(ga0 + k0, la0);
        load_lds16(ga1 + k0, la1);
        load_lds16(gb0 + k0, lb0);
        __syncthreads();
        f16x8 af[4], bfr[2];
#pragma unroll
        for (int i = 0; i < 4; ++i)
            af[i] = *(const f16x8*)&sA[(ra + i * 16) * DBK + ko];
#pragma unroll
        for (int j = 0; j < 2; ++j)
            bfr[j] = *(const f16x8*)&sB[(rb + j * 16) * DBK + ko];
#pragma unroll
        for (int i = 0; i < 4; ++i)
#pragma unroll
            for (int j = 0; j < 2; ++j)
                acc[i][j] = __builtin_amdgcn_mfma_f32_16x16x32_f16(
                    af[i], bfr[j], acc[i][j], 0, 0, 0);
        __syncthreads();
    }

    // epilogue: d = max(qn + pn - 2S, 0); pair-min via shfl_xor(1); even lanes store
    float pn[2];
    int   nn[2];
#pragma unroll
    for (int j = 0; j < 2; ++j) {
        nn[j] = n0 + wn + j * 16 + (lane & 15);
        pn[j] = pnorm[nn[j]];
    }
#pragma unroll
    for (int i = 0; i < 4; ++i) {
        const int mb = m0 + wm + i * 16 + (lane >> 4) * 4;
#pragma unroll
        for (int r = 0; r < 4; ++r) {
            const float qn = qnorm[mb + r];
#pragma unroll
            for (int j = 0; j < 2; ++j) {
                float d = fmaxf(qn + pn[j] - 2.f * acc[i][j][r], 0.f);
                float o = __shfl_xor(d, 1);
                if (!(lane & 1))
                    dists[(size_t)(mb + r) * N_CLASS + (nn[j] >> 1)] = fminf(d, o);
            }
        }
    }
}

// ---------------- per-query reduce -> per-block partial (no atomics) ----------
__global__ __launch_bounds__(256) void reduce_kernel(
    const float* __restrict__ dists, float2* __restrict__ partial)
{
    const int wave = threadIdx.x >> 6;
    const int q = blockIdx.x * 4 + wave;
    const int lane = threadIdx.x & 63;
    const float* dr = dists + (size_t)q * N_CLASS;
    __shared__ float2 s_part[4];

    const float va = dr[lane];
    const float vb = dr[lane + 64];
    float sum = va + vb;
    float bv; int bi;
    if (vb > va) { bv = vb; bi = lane + 64; } else { bv = va; bi = lane; }
    for (int off = 32; off; off >>= 1) {
        sum += __shfl_down(sum, off);
        float ov = __shfl_down(bv, off);
        int   oi = __shfl_down(bi, off);
        if (ov > bv || (ov == bv && oi < bi)) { bv = ov; bi = oi; }
    }
    if (lane == 0) {
        const int c = q >> 7;
        const float own = dr[c];
        s_part[wave] = make_float2(logf(own / sum), (bi == c) ? 1.f : 0.f);
    }
    __syncthreads();
    if (threadIdx.x == 0) {
        float2 a = s_part[0], b = s_part[1], c2 = s_part[2], d = s_part[3];
        partial[blockIdx.x] = make_float2(a.x + b.x + c2.x + d.x,
                                          a.y + b.y + c2.y + d.y);
    }
}

// ---------------- final reduce over 4096 partials (single block) --------------
__global__ __launch_bounds__(1024) void finalize_kernel(
    const float2* __restrict__ partial, float* __restrict__ out)
{
    __shared__ float sl[16], sa[16];
    const int tid = threadIdx.x;
    float l = 0.f, a = 0.f;
#pragma unroll
    for (int i = 0; i < 4; ++i) {
        float2 p = partial[tid * 4 + i];
        l += p.x; a += p.y;
    }
    for (int off = 32; off; off >>= 1) {
        l += __shfl_down(l, off);
        a += __shfl_down(a, off);
    }
    const int lane = tid & 63, wave = tid >> 6;
    if (lane == 0) { sl[wave] = l; sa[wave] = a; }
    __syncthreads();
    if (tid == 0) {
        float L = 0.f, A = 0.f;
#pragma unroll
        for (int w = 0; w < 16; ++w) { L += sl[w]; A += sa[w]; }
        out[0] = -L / (float)N_Q;
        out[1] =  A / (float)N_Q;
    }
}

// ---------------- launch ----------------
extern "C" void kernel_launch(void* const* d_in, const int* in_sizes, int n_in,
                              void* d_out, int out_size, void* d_ws, size_t ws_size,
                              hipStream_t stream)
{
    (void)in_sizes; (void)n_in; (void)out_size; (void)ws_size;
    const float* xs = (const float*)d_in[0];
    const float* xq = (const float*)d_in[1];
    const float* W  = (const float*)d_in[2];
    float* out = (float*)d_out;

    char* ws = (char*)d_ws;
    float*          z      = (float*)(ws);                        //  83,886,080 B
    unsigned short* xb     = (unsigned short*)(ws + 83886080ull); //  83,886,080 B (dead after gemm)
    _Float16*       zqh    = (_Float16*)(ws + 83886080ull);       //  alias xb: 33,554,432 B
    _Float16*       ph     = (_Float16*)(ws + 117440512ull);      //  alias xb: 524,288 B
    unsigned short* wt     = (unsigned short*)(ws + 167772160ull);//   4,194,304 B
    float*          pnorm  = (float*)(ws + 173015040ull);         //       1,024 B
    float*          qnorm  = (float*)(ws + 173016064ull);         //      65,536 B
    float*          dists  = (float*)(ws + 173081600ull);         //   8,388,608 B
    float2*         partial= (float2*)(ws + 181470208ull);        //      32,768 B

    cast_bf16<<<N_S * D_IN / 1024, 256, 0, stream>>>(xs, xb);
    cast_bf16<<<N_Q * D_IN / 1024, 256, 0, stream>>>(xq, xb + (size_t)N_S * D_IN);
    wt_kernel<<<dim3(Z_DIM / 64, D_IN / 64), 256, 0, stream>>>(W, wt);

    dim3 gA(Z_DIM / GBN, N_ROWS / GBM);   // (8, 160)
    gemm_mfma<<<gA, 256, 0, stream>>>(xb, wt, z);
    // xb dead from here; zqh/ph live in its space

    const float* zq = z + (size_t)N_S * Z_DIM;
    qnorm_cast<<<N_Q / 4, 256, 0, stream>>>(zq, qnorm, zqh);
    centroids_kernel<<<N_CLASS, 256, 0, stream>>>(z, ph, pnorm);

    dim3 gD(NPROTO / DBN, N_Q / DBM);     // (4, 128)
    dist_mfma<<<gD, 256, 0, stream>>>(zqh, ph, pnorm, qnorm, dists);

    reduce_kernel<<<N_RBLK, 256, 0, stream>>>(dists, partial);
    finalize_kernel<<<1, 1024, 0, stream>>>(partial, out);
}

// Round 5
// 404.046 us; speedup vs baseline: 4.2843x; 1.1714x over previous
//
#include <hip/hip_runtime.h>
#include <cmath>

#define N_CLASS 128
#define N_SUP   32
#define N_QRY   128
#define D_IN    2048
#define Z_DIM   1024
#define NPROTO  256
#define N_S     (N_CLASS * N_SUP)   // 4096
#define N_Q     (N_CLASS * N_QRY)   // 16384
#define N_ROWS  (N_S + N_Q)         // 20480
#define N_RBLK  (N_Q / 4)           // 4096 reduce blocks

typedef __attribute__((ext_vector_type(4))) float f32x4;
typedef __attribute__((ext_vector_type(8))) short bf16x8;
typedef _Float16 f16x8 __attribute__((ext_vector_type(8)));
typedef _Float16 f16x4 __attribute__((ext_vector_type(4)));

__device__ __forceinline__ unsigned short f2bf(float f) {
    unsigned u = __float_as_uint(f);
    u += 0x7fffu + ((u >> 16) & 1u);   // RNE
    return (unsigned short)(u >> 16);
}

__device__ __forceinline__ void load_lds16(const void* g, void* l) {
    __builtin_amdgcn_global_load_lds(
        (const __attribute__((address_space(1))) unsigned int*)g,
        (__attribute__((address_space(3))) unsigned int*)l, 16, 0, 0);
}

// ---------------- cast fp32 -> bf16 (4 floats / thread) ----------------
__global__ __launch_bounds__(256) void cast_bf16(
    const float* __restrict__ in, unsigned short* __restrict__ out)
{
    const int i = (blockIdx.x * 256 + threadIdx.x) * 4;
    float4 v = *(const float4*)(in + i);
    ushort4 o;
    o.x = f2bf(v.x); o.y = f2bf(v.y); o.z = f2bf(v.z); o.w = f2bf(v.w);
    *(ushort4*)(out + i) = o;
}

// ---------------- W (K x N fp32) -> Wt (N x K bf16), tiled transpose ----------
__global__ __launch_bounds__(256) void wt_kernel(
    const float* __restrict__ W, unsigned short* __restrict__ wt)
{
    __shared__ unsigned short t[64][65];
    const int n0 = blockIdx.x * 64;
    const int k0 = blockIdx.y * 64;
#pragma unroll
    for (int e = 0; e < 16; ++e) {
        int idx = e * 256 + threadIdx.x;
        int r = idx >> 6, c = idx & 63;            // r: k, c: n
        t[c][r] = f2bf(W[(size_t)(k0 + r) * Z_DIM + n0 + c]);
    }
    __syncthreads();
#pragma unroll
    for (int e = 0; e < 16; ++e) {
        int idx = e * 256 + threadIdx.x;
        int r = idx >> 6, c = idx & 63;            // r: n, c: k
        wt[(size_t)(n0 + r) * D_IN + k0 + c] = t[r][c];
    }
}

// ------- bf16 MFMA GEMM: z_h[20480x1024](f16) = xb @ WtT, + fused qnorm -------
#define GBM 128
#define GBN 128
#define GBK 32

__global__ __launch_bounds__(256) void gemm_mfma(
    const unsigned short* __restrict__ xb,   // 20480 x 2048 (row-major, bf16)
    const unsigned short* __restrict__ wt,   // 1024 x 2048 (N x K, bf16)
    _Float16* __restrict__ zh,               // 20480 x 1024 f16
    float* __restrict__ qnorm)               // 16384 (zero-initialized)
{
    __shared__ unsigned short sA[GBM * GBK];
    __shared__ unsigned short sB[GBN * GBK];
    const int tid  = threadIdx.x;

    // swizzle: b = 64g + 8j + k  ->  m-tile = 8g+k, n-tile = j
    // (8 XCD-consecutive blocks share one A-tile -> L2-resident A)
    const int b     = blockIdx.x + gridDim.x * blockIdx.y;
    const int m0    = ((b >> 6) * 8 + (b & 7)) * GBM;
    const int n0    = ((b >> 3) & 7) * GBN;

    const int lane = tid & 63;
    const int wave = tid >> 6;
    const int wm   = (wave >> 1) * 64;
    const int wn   = (wave & 1) * 64;

    const int f0 = tid, f1 = tid + 256;
    const unsigned short* ga0 = xb + (size_t)(m0 + (f0 >> 2)) * D_IN + ((f0 & 3) << 3);
    const unsigned short* ga1 = xb + (size_t)(m0 + (f1 >> 2)) * D_IN + ((f1 & 3) << 3);
    const unsigned short* gb0 = wt + (size_t)(n0 + (f0 >> 2)) * D_IN + ((f0 & 3) << 3);
    const unsigned short* gb1 = wt + (size_t)(n0 + (f1 >> 2)) * D_IN + ((f1 & 3) << 3);
    unsigned short* la0 = &sA[f0 * 8];
    unsigned short* la1 = &sA[f1 * 8];
    unsigned short* lb0 = &sB[f0 * 8];
    unsigned short* lb1 = &sB[f1 * 8];

    f32x4 acc[4][4];
#pragma unroll
    for (int i = 0; i < 4; ++i)
#pragma unroll
        for (int j = 0; j < 4; ++j) acc[i][j] = (f32x4){0.f, 0.f, 0.f, 0.f};

    const int ra = wm + (lane & 15);
    const int rb = wn + (lane & 15);
    const int ko = (lane >> 4) * 8;

    for (int k0 = 0; k0 < D_IN; k0 += GBK) {
        load_lds16(ga0 + k0, la0);
        load_lds16(ga1 + k0, la1);
        load_lds16(gb0 + k0, lb0);
        load_lds16(gb1 + k0, lb1);
        __syncthreads();

        bf16x8 af[4], bfr[4];
#pragma unroll
        for (int i = 0; i < 4; ++i)
            af[i] = *(const bf16x8*)&sA[(ra + i * 16) * GBK + ko];
#pragma unroll
        for (int j = 0; j < 4; ++j)
            bfr[j] = *(const bf16x8*)&sB[(rb + j * 16) * GBK + ko];
#pragma unroll
        for (int i = 0; i < 4; ++i)
#pragma unroll
            for (int j = 0; j < 4; ++j)
                acc[i][j] = __builtin_amdgcn_mfma_f32_16x16x32_bf16(
                    af[i], bfr[j], acc[i][j], 0, 0, 0);
        __syncthreads();
    }

    // epilogue: f16 store + fused row-norm (query rows only)
#pragma unroll
    for (int i = 0; i < 4; ++i) {
#pragma unroll
        for (int r = 0; r < 4; ++r) {
            const int m = m0 + wm + i * 16 + (lane >> 4) * 4 + r;
#pragma unroll
            for (int j = 0; j < 4; ++j) {
                const int n = n0 + wn + j * 16 + (lane & 15);
                zh[(size_t)m * Z_DIM + n] = (_Float16)acc[i][j][r];
            }
            float p = acc[i][0][r] * acc[i][0][r] + acc[i][1][r] * acc[i][1][r]
                    + acc[i][2][r] * acc[i][2][r] + acc[i][3][r] * acc[i][3][r];
            p += __shfl_xor(p, 1);
            p += __shfl_xor(p, 2);
            p += __shfl_xor(p, 4);
            p += __shfl_xor(p, 8);
            if (m >= N_S && (lane & 15) == 0) atomicAdd(&qnorm[m - N_S], p);
        }
    }
}

// ---- per-class assignment + centroids (f16 in/out) + fp32 proto norms ----
__global__ __launch_bounds__(256) void centroids_kernel(
    const _Float16* __restrict__ zh, _Float16* __restrict__ ph, float* __restrict__ pnorm)
{
    const int c = blockIdx.x;
    const _Float16* zc = zh + (size_t)c * N_SUP * Z_DIM;
    __shared__ int s_assign[N_SUP];
    __shared__ float red0[4], red1[4];
    const int lane = threadIdx.x & 63;
    const int wave = threadIdx.x >> 6;

    for (int s = wave; s < N_SUP; s += 4) {
        const _Float16* zr = zc + (size_t)s * Z_DIM;
        float d0 = 0.f, d1 = 0.f;
        for (int i = lane; i < Z_DIM; i += 64) {
            float v  = (float)zr[i];
            float t0 = v - (float)zc[i];
            float t1 = v - (float)zc[Z_DIM + i];
            d0 = fmaf(t0, t0, d0);
            d1 = fmaf(t1, t1, d1);
        }
        for (int off = 32; off; off >>= 1) {
            d0 += __shfl_down(d0, off);
            d1 += __shfl_down(d1, off);
        }
        if (lane == 0) s_assign[s] = (d1 < d0) ? 1 : 0;
    }
    __syncthreads();

    int cnt1 = 0;
    for (int s = 0; s < N_SUP; ++s) cnt1 += s_assign[s];
    const int cnt0 = N_SUP - cnt1;

    float n0 = 0.f, n1 = 0.f;
    for (int d = threadIdx.x; d < Z_DIM; d += 256) {
        float s0 = 0.f, s1 = 0.f;
        for (int s = 0; s < N_SUP; ++s) {
            float v = (float)zc[(size_t)s * Z_DIM + d];
            if (s_assign[s]) s1 += v; else s0 += v;
        }
        float c0 = (cnt0 > 0) ? (s0 / (float)cnt0) : (float)zc[d];
        float c1 = (cnt1 > 0) ? (s1 / (float)cnt1) : (float)zc[Z_DIM + d];
        ph[(size_t)(2 * c)     * Z_DIM + d] = (_Float16)c0;
        ph[(size_t)(2 * c + 1) * Z_DIM + d] = (_Float16)c1;
        n0 = fmaf(c0, c0, n0);
        n1 = fmaf(c1, c1, n1);
    }
    for (int off = 32; off; off >>= 1) {
        n0 += __shfl_down(n0, off);
        n1 += __shfl_down(n1, off);
    }
    if (lane == 0) { red0[wave] = n0; red1[wave] = n1; }
    __syncthreads();
    if (threadIdx.x == 0) {
        pnorm[2 * c]     = red0[0] + red0[1] + red0[2] + red0[3];
        pnorm[2 * c + 1] = red1[0] + red1[1] + red1[2] + red1[3];
    }
}

// ---- dist via f16 MFMA: S=zq@protos^T; dists[q][c]=min_k max(qn+pn-2S,0) ----
#define DBM 128
#define DBN 64
#define DBK 32
__global__ __launch_bounds__(256) void dist_mfma(
    const _Float16* __restrict__ zqh,   // 16384 x 1024
    const _Float16* __restrict__ ph,    // 256 x 1024 (N x K)
    const float* __restrict__ pnorm, const float* __restrict__ qnorm,
    float* __restrict__ dists)          // 16384 x 128
{
    __shared__ _Float16 sA[DBM * DBK];  // 8 KB
    __shared__ _Float16 sB[DBN * DBK];  // 4 KB
    const int tid  = threadIdx.x;
    const int m0   = blockIdx.y * DBM;
    const int n0   = blockIdx.x * DBN;
    const int lane = tid & 63;
    const int wave = tid >> 6;
    const int wm   = (wave >> 1) * 64;
    const int wn   = (wave & 1) * 32;

    const int f0 = tid, f1 = tid + 256;
    const _Float16* ga0 = zqh + (size_t)(m0 + (f0 >> 2)) * Z_DIM + ((f0 & 3) << 3);
    const _Float16* ga1 = zqh + (size_t)(m0 + (f1 >> 2)) * Z_DIM + ((f1 & 3) << 3);
    const _Float16* gb0 = ph  + (size_t)(n0 + (tid >> 2)) * Z_DIM + ((tid & 3) << 3);
    _Float16* la0 = &sA[f0 * 8];
    _Float16* la1 = &sA[f1 * 8];
    _Float16* lb0 = &sB[tid * 8];

    f32x4 acc[4][2];
#pragma unroll
    for (int i = 0; i < 4; ++i)
#pragma unroll
        for (int j = 0; j < 2; ++j) acc[i][j] = (f32x4){0.f, 0.f, 0.f, 0.f};

    const int ra = wm + (lane & 15);
    const int rb = wn + (lane & 15);
    const int ko = (lane >> 4) * 8;

    for (int k0 = 0; k0 < Z_DIM; k0 += DBK) {
        load_lds16(ga0 + k0, la0);
        load_lds16(ga1 + k0, la1);
        load_lds16(gb0 + k0, lb0);
        __syncthreads();
        f16x8 af[4], bfr[2];
#pragma unroll
        for (int i = 0; i < 4; ++i)
            af[i] = *(const f16x8*)&sA[(ra + i * 16) * DBK + ko];
#pragma unroll
        for (int j = 0; j < 2; ++j)
            bfr[j] = *(const f16x8*)&sB[(rb + j * 16) * DBK + ko];
#pragma unroll
        for (int i = 0; i < 4; ++i)
#pragma unroll
            for (int j = 0; j < 2; ++j)
                acc[i][j] = __builtin_amdgcn_mfma_f32_16x16x32_f16(
                    af[i], bfr[j], acc[i][j], 0, 0, 0);
        __syncthreads();
    }

    float pn[2];
    int   nn[2];
#pragma unroll
    for (int j = 0; j < 2; ++j) {
        nn[j] = n0 + wn + j * 16 + (lane & 15);
        pn[j] = pnorm[nn[j]];
    }
#pragma unroll
    for (int i = 0; i < 4; ++i) {
        const int mb = m0 + wm + i * 16 + (lane >> 4) * 4;
#pragma unroll
        for (int r = 0; r < 4; ++r) {
            const float qn = qnorm[mb + r];
#pragma unroll
            for (int j = 0; j < 2; ++j) {
                float d = fmaxf(qn + pn[j] - 2.f * acc[i][j][r], 0.f);
                float o = __shfl_xor(d, 1);
                if (!(lane & 1))
                    dists[(size_t)(mb + r) * N_CLASS + (nn[j] >> 1)] = fminf(d, o);
            }
        }
    }
}

// ---------------- per-query reduce -> per-block partial (no atomics) ----------
__global__ __launch_bounds__(256) void reduce_kernel(
    const float* __restrict__ dists, float2* __restrict__ partial)
{
    const int wave = threadIdx.x >> 6;
    const int q = blockIdx.x * 4 + wave;
    const int lane = threadIdx.x & 63;
    const float* dr = dists + (size_t)q * N_CLASS;
    __shared__ float2 s_part[4];

    const float va = dr[lane];
    const float vb = dr[lane + 64];
    float sum = va + vb;
    float bv; int bi;
    if (vb > va) { bv = vb; bi = lane + 64; } else { bv = va; bi = lane; }
    for (int off = 32; off; off >>= 1) {
        sum += __shfl_down(sum, off);
        float ov = __shfl_down(bv, off);
        int   oi = __shfl_down(bi, off);
        if (ov > bv || (ov == bv && oi < bi)) { bv = ov; bi = oi; }
    }
    if (lane == 0) {
        const int c = q >> 7;
        const float own = dr[c];
        s_part[wave] = make_float2(logf(own / sum), (bi == c) ? 1.f : 0.f);
    }
    __syncthreads();
    if (threadIdx.x == 0) {
        float2 a = s_part[0], b = s_part[1], c2 = s_part[2], d = s_part[3];
        partial[blockIdx.x] = make_float2(a.x + b.x + c2.x + d.x,
                                          a.y + b.y + c2.y + d.y);
    }
}

// ---------------- final reduce over 4096 partials (single block) --------------
__global__ __launch_bounds__(1024) void finalize_kernel(
    const float2* __restrict__ partial, float* __restrict__ out)
{
    __shared__ float sl[16], sa[16];
    const int tid = threadIdx.x;
    float l = 0.f, a = 0.f;
#pragma unroll
    for (int i = 0; i < 4; ++i) {
        float2 p = partial[tid * 4 + i];
        l += p.x; a += p.y;
    }
    for (int off = 32; off; off >>= 1) {
        l += __shfl_down(l, off);
        a += __shfl_down(a, off);
    }
    const int lane = tid & 63, wave = tid >> 6;
    if (lane == 0) { sl[wave] = l; sa[wave] = a; }
    __syncthreads();
    if (tid == 0) {
        float L = 0.f, A = 0.f;
#pragma unroll
        for (int w = 0; w < 16; ++w) { L += sl[w]; A += sa[w]; }
        out[0] = -L / (float)N_Q;
        out[1] =  A / (float)N_Q;
    }
}

// ---------------- launch ----------------
extern "C" void kernel_launch(void* const* d_in, const int* in_sizes, int n_in,
                              void* d_out, int out_size, void* d_ws, size_t ws_size,
                              hipStream_t stream)
{
    (void)in_sizes; (void)n_in; (void)out_size; (void)ws_size;
    const float* xs = (const float*)d_in[0];
    const float* xq = (const float*)d_in[1];
    const float* W  = (const float*)d_in[2];
    float* out = (float*)d_out;

    char* ws = (char*)d_ws;
    _Float16*       zh     = (_Float16*)(ws);                     //  41,943,040 B
    unsigned short* xb     = (unsigned short*)(ws + 41943040ull); //  83,886,080 B
    unsigned short* wt     = (unsigned short*)(ws + 125829120ull);//   4,194,304 B
    _Float16*       ph     = (_Float16*)(ws + 130023424ull);      //     524,288 B
    float*          pnorm  = (float*)(ws + 130547712ull);         //       1,024 B
    float*          qnorm  = (float*)(ws + 130548736ull);         //      65,536 B
    float*          dists  = (float*)(ws + 130614272ull);         //   8,388,608 B
    float2*         partial= (float2*)(ws + 139002880ull);        //      32,768 B

    cast_bf16<<<N_S * D_IN / 1024, 256, 0, stream>>>(xs, xb);
    cast_bf16<<<N_Q * D_IN / 1024, 256, 0, stream>>>(xq, xb + (size_t)N_S * D_IN);
    wt_kernel<<<dim3(Z_DIM / 64, D_IN / 64), 256, 0, stream>>>(W, wt);
    hipMemsetAsync(qnorm, 0, N_Q * sizeof(float), stream);

    dim3 gA(Z_DIM / GBN, N_ROWS / GBM);   // (8, 160) -> swizzled in-kernel
    gemm_mfma<<<gA, 256, 0, stream>>>(xb, wt, zh, qnorm);

    const _Float16* zqh = zh + (size_t)N_S * Z_DIM;
    centroids_kernel<<<N_CLASS, 256, 0, stream>>>(zh, ph, pnorm);

    dim3 gD(NPROTO / DBN, N_Q / DBM);     // (4, 128)
    dist_mfma<<<gD, 256, 0, stream>>>(zqh, ph, pnorm, qnorm, dists);

    reduce_kernel<<<N_RBLK, 256, 0, stream>>>(dists, partial);
    finalize_kernel<<<1, 1024, 0, stream>>>(partial, out);
}

// Round 6
// 376.342 us; speedup vs baseline: 4.5997x; 1.0736x over previous
//
#include <hip/hip_runtime.h>
#include <cmath>

#define N_CLASS 128
#define N_SUP   32
#define N_QRY   128
#define D_IN    2048
#define Z_DIM   1024
#define NPROTO  256
#define N_S     (N_CLASS * N_SUP)   // 4096
#define N_Q     (N_CLASS * N_QRY)   // 16384
#define N_ROWS  (N_S + N_Q)         // 20480
#define N_RBLK  (N_Q / 4)           // 4096 reduce blocks

typedef __attribute__((ext_vector_type(4))) float f32x4;
typedef __attribute__((ext_vector_type(8))) short bf16x8;
typedef _Float16 f16x8 __attribute__((ext_vector_type(8)));
typedef _Float16 f16x4 __attribute__((ext_vector_type(4)));

__device__ __forceinline__ unsigned short f2bf(float f) {
    unsigned u = __float_as_uint(f);
    u += 0x7fffu + ((u >> 16) & 1u);   // RNE
    return (unsigned short)(u >> 16);
}

__device__ __forceinline__ void load_lds16(const void* g, void* l) {
    __builtin_amdgcn_global_load_lds(
        (const __attribute__((address_space(1))) unsigned int*)g,
        (__attribute__((address_space(3))) unsigned int*)l, 16, 0, 0);
}

// ---------------- cast fp32 -> bf16 (4 floats / thread) ----------------
__global__ __launch_bounds__(256) void cast_bf16(
    const float* __restrict__ in, unsigned short* __restrict__ out)
{
    const int i = (blockIdx.x * 256 + threadIdx.x) * 4;
    float4 v = *(const float4*)(in + i);
    ushort4 o;
    o.x = f2bf(v.x); o.y = f2bf(v.y); o.z = f2bf(v.z); o.w = f2bf(v.w);
    *(ushort4*)(out + i) = o;
}

// ---------------- W (K x N fp32) -> Wt (N x K bf16), tiled transpose ----------
__global__ __launch_bounds__(256) void wt_kernel(
    const float* __restrict__ W, unsigned short* __restrict__ wt)
{
    __shared__ unsigned short t[64][65];
    const int n0 = blockIdx.x * 64;
    const int k0 = blockIdx.y * 64;
#pragma unroll
    for (int e = 0; e < 16; ++e) {
        int idx = e * 256 + threadIdx.x;
        int r = idx >> 6, c = idx & 63;            // r: k, c: n
        t[c][r] = f2bf(W[(size_t)(k0 + r) * Z_DIM + n0 + c]);
    }
    __syncthreads();
#pragma unroll
    for (int e = 0; e < 16; ++e) {
        int idx = e * 256 + threadIdx.x;
        int r = idx >> 6, c = idx & 63;            // r: n, c: k
        wt[(size_t)(n0 + r) * D_IN + k0 + c] = t[r][c];
    }
}

// ------- bf16 MFMA GEMM: z_h[20480x1024](f16) = xb @ WtT, + fused qnorm -------
#define GBM 128
#define GBN 128
#define GBK 32

__global__ __launch_bounds__(256) void gemm_mfma(
    const unsigned short* __restrict__ xb,   // 20480 x 2048 (row-major, bf16)
    const unsigned short* __restrict__ wt,   // 1024 x 2048 (N x K, bf16)
    _Float16* __restrict__ zh,               // 20480 x 1024 f16
    float* __restrict__ qnorm)               // 16384 (zero-initialized)
{
    __shared__ unsigned short sA[GBM * GBK];
    __shared__ unsigned short sB[GBN * GBK];
    const int tid  = threadIdx.x;

    // swizzle: b = 64g + 8j + k  ->  m-tile = 8g+k, n-tile = j
    const int b     = blockIdx.x + gridDim.x * blockIdx.y;
    const int m0    = ((b >> 6) * 8 + (b & 7)) * GBM;
    const int n0    = ((b >> 3) & 7) * GBN;

    const int lane = tid & 63;
    const int wave = tid >> 6;
    const int wm   = (wave >> 1) * 64;
    const int wn   = (wave & 1) * 64;

    const int f0 = tid, f1 = tid + 256;
    const unsigned short* ga0 = xb + (size_t)(m0 + (f0 >> 2)) * D_IN + ((f0 & 3) << 3);
    const unsigned short* ga1 = xb + (size_t)(m0 + (f1 >> 2)) * D_IN + ((f1 & 3) << 3);
    const unsigned short* gb0 = wt + (size_t)(n0 + (f0 >> 2)) * D_IN + ((f0 & 3) << 3);
    const unsigned short* gb1 = wt + (size_t)(n0 + (f1 >> 2)) * D_IN + ((f1 & 3) << 3);
    unsigned short* la0 = &sA[f0 * 8];
    unsigned short* la1 = &sA[f1 * 8];
    unsigned short* lb0 = &sB[f0 * 8];
    unsigned short* lb1 = &sB[f1 * 8];

    f32x4 acc[4][4];
#pragma unroll
    for (int i = 0; i < 4; ++i)
#pragma unroll
        for (int j = 0; j < 4; ++j) acc[i][j] = (f32x4){0.f, 0.f, 0.f, 0.f};

    const int ra = wm + (lane & 15);
    const int rb = wn + (lane & 15);
    const int ko = (lane >> 4) * 8;

    for (int k0 = 0; k0 < D_IN; k0 += GBK) {
        load_lds16(ga0 + k0, la0);
        load_lds16(ga1 + k0, la1);
        load_lds16(gb0 + k0, lb0);
        load_lds16(gb1 + k0, lb1);
        __syncthreads();

        bf16x8 af[4], bfr[4];
#pragma unroll
        for (int i = 0; i < 4; ++i)
            af[i] = *(const bf16x8*)&sA[(ra + i * 16) * GBK + ko];
#pragma unroll
        for (int j = 0; j < 4; ++j)
            bfr[j] = *(const bf16x8*)&sB[(rb + j * 16) * GBK + ko];
#pragma unroll
        for (int i = 0; i < 4; ++i)
#pragma unroll
            for (int j = 0; j < 4; ++j)
                acc[i][j] = __builtin_amdgcn_mfma_f32_16x16x32_bf16(
                    af[i], bfr[j], acc[i][j], 0, 0, 0);
        __syncthreads();
    }

    // epilogue: f16 store + fused row-norm (query rows only)
#pragma unroll
    for (int i = 0; i < 4; ++i) {
#pragma unroll
        for (int r = 0; r < 4; ++r) {
            const int m = m0 + wm + i * 16 + (lane >> 4) * 4 + r;
#pragma unroll
            for (int j = 0; j < 4; ++j) {
                const int n = n0 + wn + j * 16 + (lane & 15);
                zh[(size_t)m * Z_DIM + n] = (_Float16)acc[i][j][r];
            }
            float p = acc[i][0][r] * acc[i][0][r] + acc[i][1][r] * acc[i][1][r]
                    + acc[i][2][r] * acc[i][2][r] + acc[i][3][r] * acc[i][3][r];
            p += __shfl_xor(p, 1);
            p += __shfl_xor(p, 2);
            p += __shfl_xor(p, 4);
            p += __shfl_xor(p, 8);
            if (m >= N_S && (lane & 15) == 0) atomicAdd(&qnorm[m - N_S], p);
        }
    }
}

// ---- assignment: one wave per support row; argmin over {init0, init1} --------
__global__ __launch_bounds__(256) void assign_kernel(
    const _Float16* __restrict__ zh, int* __restrict__ assign)
{
    const int wave = threadIdx.x >> 6, lane = threadIdx.x & 63;
    const int sg = blockIdx.x * 4 + wave;       // 0..4095
    const int c  = sg >> 5;
    const _Float16* zc = zh + (size_t)c * N_SUP * Z_DIM;
    const _Float16* zr = zc + (size_t)(sg & 31) * Z_DIM;
    float d0 = 0.f, d1 = 0.f;
#pragma unroll
    for (int it = 0; it < 2; ++it) {
        const int idx = (it * 64 + lane) * 8;
        f16x8 v  = *(const f16x8*)(zr + idx);
        f16x8 i0 = *(const f16x8*)(zc + idx);
        f16x8 i1 = *(const f16x8*)(zc + Z_DIM + idx);
#pragma unroll
        for (int e = 0; e < 8; ++e) {
            float t0 = (float)v[e] - (float)i0[e];
            float t1 = (float)v[e] - (float)i1[e];
            d0 = fmaf(t0, t0, d0);
            d1 = fmaf(t1, t1, d1);
        }
    }
    for (int off = 32; off; off >>= 1) {
        d0 += __shfl_down(d0, off);
        d1 += __shfl_down(d1, off);
    }
    if (lane == 0) assign[sg] = (d1 < d0) ? 1 : 0;
}

// ---- centroids: block = (d-chunk, class); one thread per dim -----------------
__global__ __launch_bounds__(256) void centroid_kernel(
    const _Float16* __restrict__ zh, const int* __restrict__ assign,
    _Float16* __restrict__ ph, float* __restrict__ pnorm)   // pnorm zero-init
{
    const int c = blockIdx.y;
    const int d = blockIdx.x * 256 + threadIdx.x;
    __shared__ int sa_[N_SUP];
    if (threadIdx.x < N_SUP) sa_[threadIdx.x] = assign[c * N_SUP + threadIdx.x];
    __syncthreads();
    int cnt1 = 0;
#pragma unroll
    for (int s = 0; s < N_SUP; ++s) cnt1 += sa_[s];
    const int cnt0 = N_SUP - cnt1;

    const _Float16* zc = zh + (size_t)c * N_SUP * Z_DIM;
    float s0 = 0.f, s1 = 0.f;
#pragma unroll
    for (int s = 0; s < N_SUP; ++s) {
        float v = (float)zc[(size_t)s * Z_DIM + d];
        if (sa_[s]) s1 += v; else s0 += v;
    }
    float c0 = (cnt0 > 0) ? (s0 / (float)cnt0) : (float)zc[d];
    float c1 = (cnt1 > 0) ? (s1 / (float)cnt1) : (float)zc[Z_DIM + d];
    ph[(size_t)(2 * c)     * Z_DIM + d] = (_Float16)c0;
    ph[(size_t)(2 * c + 1) * Z_DIM + d] = (_Float16)c1;

    float n0 = c0 * c0, n1 = c1 * c1;
    for (int off = 32; off; off >>= 1) {
        n0 += __shfl_down(n0, off);
        n1 += __shfl_down(n1, off);
    }
    if ((threadIdx.x & 63) == 0) {
        atomicAdd(&pnorm[2 * c],     n0);
        atomicAdd(&pnorm[2 * c + 1], n1);
    }
}

// ---- dist via f16 MFMA, DBK=64, XOR-swizzled LDS (b128 conflict floor) -------
#define DBM 128
#define DBN 64
#define DBK 64
__global__ __launch_bounds__(256) void dist_mfma(
    const _Float16* __restrict__ zqh,   // 16384 x 1024
    const _Float16* __restrict__ ph,    // 256 x 1024 (N x K)
    const float* __restrict__ pnorm, const float* __restrict__ qnorm,
    float* __restrict__ dists)          // 16384 x 128
{
    __shared__ _Float16 sA[DBM * DBK];  // 16 KB
    __shared__ _Float16 sB[DBN * DBK];  // 8 KB
    const int tid  = threadIdx.x;
    const int m0   = blockIdx.y * DBM;
    const int n0   = blockIdx.x * DBN;
    const int lane = tid & 63;
    const int wave = tid >> 6;
    const int wm   = (wave >> 1) * 64;
    const int wn   = (wave & 1) * 32;

    // slot f: row f>>3, sub f&7; global k-sub fetched = (f&7) ^ sw3(row)
    const _Float16* ga[4]; _Float16* la[4];
#pragma unroll
    for (int i = 0; i < 4; ++i) {
        int f = tid + 256 * i;
        int r = f >> 3, s = f & 7;
        int gs = s ^ ((r ^ (r >> 3)) & 7);
        ga[i] = zqh + (size_t)(m0 + r) * Z_DIM + gs * 8;
        la[i] = &sA[f * 8];
    }
    const _Float16* gb[2]; _Float16* lb[2];
#pragma unroll
    for (int i = 0; i < 2; ++i) {
        int f = tid + 256 * i;
        int r = f >> 3, s = f & 7;
        int gs = s ^ ((r ^ (r >> 3)) & 7);
        gb[i] = ph + (size_t)(n0 + r) * Z_DIM + gs * 8;
        lb[i] = &sB[f * 8];
    }

    f32x4 acc[4][2];
#pragma unroll
    for (int i = 0; i < 4; ++i)
#pragma unroll
        for (int j = 0; j < 2; ++j) acc[i][j] = (f32x4){0.f, 0.f, 0.f, 0.f};

    const int ra = wm + (lane & 15);
    const int rb = wn + (lane & 15);
    const int kq = lane >> 4;           // k-quarter within 32-k half

    for (int k0 = 0; k0 < Z_DIM; k0 += DBK) {
#pragma unroll
        for (int i = 0; i < 4; ++i) load_lds16(ga[i] + k0, la[i]);
#pragma unroll
        for (int i = 0; i < 2; ++i) load_lds16(gb[i] + k0, lb[i]);
        __syncthreads();
#pragma unroll
        for (int h = 0; h < 2; ++h) {
            f16x8 af[4], bfr[2];
#pragma unroll
            for (int i = 0; i < 4; ++i) {
                const int R = ra + i * 16;
                const int s = (h * 4 + kq) ^ ((R ^ (R >> 3)) & 7);
                af[i] = *(const f16x8*)&sA[R * DBK + s * 8];
            }
#pragma unroll
            for (int j = 0; j < 2; ++j) {
                const int R = rb + j * 16;
                const int s = (h * 4 + kq) ^ ((R ^ (R >> 3)) & 7);
                bfr[j] = *(const f16x8*)&sB[R * DBK + s * 8];
            }
#pragma unroll
            for (int i = 0; i < 4; ++i)
#pragma unroll
                for (int j = 0; j < 2; ++j)
                    acc[i][j] = __builtin_amdgcn_mfma_f32_16x16x32_f16(
                        af[i], bfr[j], acc[i][j], 0, 0, 0);
        }
        __syncthreads();
    }

    float pn[2];
    int   nn[2];
#pragma unroll
    for (int j = 0; j < 2; ++j) {
        nn[j] = n0 + wn + j * 16 + (lane & 15);
        pn[j] = pnorm[nn[j]];
    }
#pragma unroll
    for (int i = 0; i < 4; ++i) {
        const int mb = m0 + wm + i * 16 + (lane >> 4) * 4;
#pragma unroll
        for (int r = 0; r < 4; ++r) {
            const float qn = qnorm[mb + r];
#pragma unroll
            for (int j = 0; j < 2; ++j) {
                float d = fmaxf(qn + pn[j] - 2.f * acc[i][j][r], 0.f);
                float o = __shfl_xor(d, 1);
                if (!(lane & 1))
                    dists[(size_t)(mb + r) * N_CLASS + (nn[j] >> 1)] = fminf(d, o);
            }
        }
    }
}

// ---------------- per-query reduce -> per-block partial (no atomics) ----------
__global__ __launch_bounds__(256) void reduce_kernel(
    const float* __restrict__ dists, float2* __restrict__ partial)
{
    const int wave = threadIdx.x >> 6;
    const int q = blockIdx.x * 4 + wave;
    const int lane = threadIdx.x & 63;
    const float* dr = dists + (size_t)q * N_CLASS;
    __shared__ float2 s_part[4];

    const float va = dr[lane];
    const float vb = dr[lane + 64];
    float sum = va + vb;
    float bv; int bi;
    if (vb > va) { bv = vb; bi = lane + 64; } else { bv = va; bi = lane; }
    for (int off = 32; off; off >>= 1) {
        sum += __shfl_down(sum, off);
        float ov = __shfl_down(bv, off);
        int   oi = __shfl_down(bi, off);
        if (ov > bv || (ov == bv && oi < bi)) { bv = ov; bi = oi; }
    }
    if (lane == 0) {
        const int c = q >> 7;
        const float own = dr[c];
        s_part[wave] = make_float2(logf(own / sum), (bi == c) ? 1.f : 0.f);
    }
    __syncthreads();
    if (threadIdx.x == 0) {
        float2 a = s_part[0], b = s_part[1], c2 = s_part[2], d = s_part[3];
        partial[blockIdx.x] = make_float2(a.x + b.x + c2.x + d.x,
                                          a.y + b.y + c2.y + d.y);
    }
}

// ---------------- final reduce over 4096 partials (single block) --------------
__global__ __launch_bounds__(1024) void finalize_kernel(
    const float2* __restrict__ partial, float* __restrict__ out)
{
    __shared__ float sl[16], sa[16];
    const int tid = threadIdx.x;
    float l = 0.f, a = 0.f;
#pragma unroll
    for (int i = 0; i < 4; ++i) {
        float2 p = partial[tid * 4 + i];
        l += p.x; a += p.y;
    }
    for (int off = 32; off; off >>= 1) {
        l += __shfl_down(l, off);
        a += __shfl_down(a, off);
    }
    const int lane = tid & 63, wave = tid >> 6;
    if (lane == 0) { sl[wave] = l; sa[wave] = a; }
    __syncthreads();
    if (tid == 0) {
        float L = 0.f, A = 0.f;
#pragma unroll
        for (int w = 0; w < 16; ++w) { L += sl[w]; A += sa[w]; }
        out[0] = -L / (float)N_Q;
        out[1] =  A / (float)N_Q;
    }
}

// ---------------- launch ----------------
extern "C" void kernel_launch(void* const* d_in, const int* in_sizes, int n_in,
                              void* d_out, int out_size, void* d_ws, size_t ws_size,
                              hipStream_t stream)
{
    (void)in_sizes; (void)n_in; (void)out_size; (void)ws_size;
    const float* xs = (const float*)d_in[0];
    const float* xq = (const float*)d_in[1];
    const float* W  = (const float*)d_in[2];
    float* out = (float*)d_out;

    char* ws = (char*)d_ws;
    _Float16*       zh     = (_Float16*)(ws);                     //  41,943,040 B
    unsigned short* xb     = (unsigned short*)(ws + 41943040ull); //  83,886,080 B
    unsigned short* wt     = (unsigned short*)(ws + 125829120ull);//   4,194,304 B
    _Float16*       ph     = (_Float16*)(ws + 130023424ull);      //     524,288 B
    float*          pnorm  = (float*)(ws + 130547712ull);         //       1,024 B
    float*          qnorm  = (float*)(ws + 130548736ull);         //      65,536 B
    float*          dists  = (float*)(ws + 130614272ull);         //   8,388,608 B
    float2*         partial= (float2*)(ws + 139002880ull);        //      32,768 B
    int*            assign = (int*)(ws + 139035648ull);           //      16,384 B

    cast_bf16<<<N_S * D_IN / 1024, 256, 0, stream>>>(xs, xb);
    cast_bf16<<<N_Q * D_IN / 1024, 256, 0, stream>>>(xq, xb + (size_t)N_S * D_IN);
    wt_kernel<<<dim3(Z_DIM / 64, D_IN / 64), 256, 0, stream>>>(W, wt);
    hipMemsetAsync(pnorm, 0, 1024 + N_Q * sizeof(float), stream);  // pnorm+qnorm contiguous

    dim3 gA(Z_DIM / GBN, N_ROWS / GBM);   // (8, 160) -> swizzled in-kernel
    gemm_mfma<<<gA, 256, 0, stream>>>(xb, wt, zh, qnorm);

    assign_kernel<<<N_S / 4, 256, 0, stream>>>(zh, assign);
    centroid_kernel<<<dim3(Z_DIM / 256, N_CLASS), 256, 0, stream>>>(zh, assign, ph, pnorm);

    const _Float16* zqh = zh + (size_t)N_S * Z_DIM;
    dim3 gD(NPROTO / DBN, N_Q / DBM);     // (4, 128)
    dist_mfma<<<gD, 256, 0, stream>>>(zqh, ph, pnorm, qnorm, dists);

    reduce_kernel<<<N_RBLK, 256, 0, stream>>>(dists, partial);
    finalize_kernel<<<1, 1024, 0, stream>>>(partial, out);
}

// Round 7
// 371.561 us; speedup vs baseline: 4.6589x; 1.0129x over previous
//
#include <hip/hip_runtime.h>
#include <cmath>

#define N_CLASS 128
#define N_SUP   32
#define N_QRY   128
#define D_IN    2048
#define Z_DIM   1024
#define NPROTO  256
#define N_S     (N_CLASS * N_SUP)   // 4096
#define N_Q     (N_CLASS * N_QRY)   // 16384
#define N_ROWS  (N_S + N_Q)         // 20480

typedef __attribute__((ext_vector_type(4))) float f32x4;
typedef __attribute__((ext_vector_type(8))) short bf16x8;
typedef _Float16 f16x8 __attribute__((ext_vector_type(8)));

__device__ __forceinline__ unsigned short f2bf(float f) {
    unsigned u = __float_as_uint(f);
    u += 0x7fffu + ((u >> 16) & 1u);   // RNE
    return (unsigned short)(u >> 16);
}

__device__ __forceinline__ void load_lds16(const void* g, void* l) {
    __builtin_amdgcn_global_load_lds(
        (const __attribute__((address_space(1))) unsigned int*)g,
        (__attribute__((address_space(3))) unsigned int*)l, 16, 0, 0);
}

// -------- cast fp32 -> bf16, both inputs in one launch (4 floats/thread) ------
__global__ __launch_bounds__(256) void cast_all(
    const float* __restrict__ xs, const float* __restrict__ xq,
    unsigned short* __restrict__ out)
{
    const int i = (blockIdx.x * 256 + threadIdx.x) * 4;
    const float* src = (i < N_S * D_IN) ? (xs + i) : (xq + (i - N_S * D_IN));
    float4 v = *(const float4*)src;
    ushort4 o;
    o.x = f2bf(v.x); o.y = f2bf(v.y); o.z = f2bf(v.z); o.w = f2bf(v.w);
    *(ushort4*)(out + i) = o;
}

// ---------------- W (K x N fp32) -> Wt (N x K bf16), tiled transpose ----------
__global__ __launch_bounds__(256) void wt_kernel(
    const float* __restrict__ W, unsigned short* __restrict__ wt)
{
    __shared__ unsigned short t[64][65];
    const int n0 = blockIdx.x * 64;
    const int k0 = blockIdx.y * 64;
#pragma unroll
    for (int e = 0; e < 16; ++e) {
        int idx = e * 256 + threadIdx.x;
        int r = idx >> 6, c = idx & 63;            // r: k, c: n
        t[c][r] = f2bf(W[(size_t)(k0 + r) * Z_DIM + n0 + c]);
    }
    __syncthreads();
#pragma unroll
    for (int e = 0; e < 16; ++e) {
        int idx = e * 256 + threadIdx.x;
        int r = idx >> 6, c = idx & 63;            // r: n, c: k
        wt[(size_t)(n0 + r) * D_IN + k0 + c] = t[r][c];
    }
}

// ------- bf16 MFMA GEMM: z_h[20480x1024](f16) = xb @ WtT, + fused qnorm -------
#define GBM 128
#define GBN 128
#define GBK 32

__global__ __launch_bounds__(256) void gemm_mfma(
    const unsigned short* __restrict__ xb,   // 20480 x 2048 (row-major, bf16)
    const unsigned short* __restrict__ wt,   // 1024 x 2048 (N x K, bf16)
    _Float16* __restrict__ zh,               // 20480 x 1024 f16
    float* __restrict__ qnorm)               // 16384 (zero-initialized)
{
    __shared__ unsigned short sA[GBM * GBK];
    __shared__ unsigned short sB[GBN * GBK];
    const int tid  = threadIdx.x;

    // swizzle: b = 64g + 8j + k  ->  m-tile = 8g+k, n-tile = j
    const int b     = blockIdx.x + gridDim.x * blockIdx.y;
    const int m0    = ((b >> 6) * 8 + (b & 7)) * GBM;
    const int n0    = ((b >> 3) & 7) * GBN;

    const int lane = tid & 63;
    const int wave = tid >> 6;
    const int wm   = (wave >> 1) * 64;
    const int wn   = (wave & 1) * 64;

    const int f0 = tid, f1 = tid + 256;
    const unsigned short* ga0 = xb + (size_t)(m0 + (f0 >> 2)) * D_IN + ((f0 & 3) << 3);
    const unsigned short* ga1 = xb + (size_t)(m0 + (f1 >> 2)) * D_IN + ((f1 & 3) << 3);
    const unsigned short* gb0 = wt + (size_t)(n0 + (f0 >> 2)) * D_IN + ((f0 & 3) << 3);
    const unsigned short* gb1 = wt + (size_t)(n0 + (f1 >> 2)) * D_IN + ((f1 & 3) << 3);
    unsigned short* la0 = &sA[f0 * 8];
    unsigned short* la1 = &sA[f1 * 8];
    unsigned short* lb0 = &sB[f0 * 8];
    unsigned short* lb1 = &sB[f1 * 8];

    f32x4 acc[4][4];
#pragma unroll
    for (int i = 0; i < 4; ++i)
#pragma unroll
        for (int j = 0; j < 4; ++j) acc[i][j] = (f32x4){0.f, 0.f, 0.f, 0.f};

    const int ra = wm + (lane & 15);
    const int rb = wn + (lane & 15);
    const int ko = (lane >> 4) * 8;

    for (int k0 = 0; k0 < D_IN; k0 += GBK) {
        load_lds16(ga0 + k0, la0);
        load_lds16(ga1 + k0, la1);
        load_lds16(gb0 + k0, lb0);
        load_lds16(gb1 + k0, lb1);
        __syncthreads();

        bf16x8 af[4], bfr[4];
#pragma unroll
        for (int i = 0; i < 4; ++i)
            af[i] = *(const bf16x8*)&sA[(ra + i * 16) * GBK + ko];
#pragma unroll
        for (int j = 0; j < 4; ++j)
            bfr[j] = *(const bf16x8*)&sB[(rb + j * 16) * GBK + ko];
#pragma unroll
        for (int i = 0; i < 4; ++i)
#pragma unroll
            for (int j = 0; j < 4; ++j)
                acc[i][j] = __builtin_amdgcn_mfma_f32_16x16x32_bf16(
                    af[i], bfr[j], acc[i][j], 0, 0, 0);
        __syncthreads();
    }

    // epilogue: f16 store + fused row-norm (query rows only)
#pragma unroll
    for (int i = 0; i < 4; ++i) {
#pragma unroll
        for (int r = 0; r < 4; ++r) {
            const int m = m0 + wm + i * 16 + (lane >> 4) * 4 + r;
#pragma unroll
            for (int j = 0; j < 4; ++j) {
                const int n = n0 + wn + j * 16 + (lane & 15);
                zh[(size_t)m * Z_DIM + n] = (_Float16)acc[i][j][r];
            }
            float p = acc[i][0][r] * acc[i][0][r] + acc[i][1][r] * acc[i][1][r]
                    + acc[i][2][r] * acc[i][2][r] + acc[i][3][r] * acc[i][3][r];
            p += __shfl_xor(p, 1);
            p += __shfl_xor(p, 2);
            p += __shfl_xor(p, 4);
            p += __shfl_xor(p, 8);
            if (m >= N_S && (lane & 15) == 0) atomicAdd(&qnorm[m - N_S], p);
        }
    }
}

// ---- assignment: one wave per support row; argmin over {init0, init1} --------
__global__ __launch_bounds__(256) void assign_kernel(
    const _Float16* __restrict__ zh, int* __restrict__ assign)
{
    const int wave = threadIdx.x >> 6, lane = threadIdx.x & 63;
    const int sg = blockIdx.x * 4 + wave;       // 0..4095
    const int c  = sg >> 5;
    const _Float16* zc = zh + (size_t)c * N_SUP * Z_DIM;
    const _Float16* zr = zc + (size_t)(sg & 31) * Z_DIM;
    float d0 = 0.f, d1 = 0.f;
#pragma unroll
    for (int it = 0; it < 2; ++it) {
        const int idx = (it * 64 + lane) * 8;
        f16x8 v  = *(const f16x8*)(zr + idx);
        f16x8 i0 = *(const f16x8*)(zc + idx);
        f16x8 i1 = *(const f16x8*)(zc + Z_DIM + idx);
#pragma unroll
        for (int e = 0; e < 8; ++e) {
            float t0 = (float)v[e] - (float)i0[e];
            float t1 = (float)v[e] - (float)i1[e];
            d0 = fmaf(t0, t0, d0);
            d1 = fmaf(t1, t1, d1);
        }
    }
    for (int off = 32; off; off >>= 1) {
        d0 += __shfl_down(d0, off);
        d1 += __shfl_down(d1, off);
    }
    if (lane == 0) assign[sg] = (d1 < d0) ? 1 : 0;
}

// ---- centroids: block = (d-chunk, class); one thread per dim -----------------
__global__ __launch_bounds__(256) void centroid_kernel(
    const _Float16* __restrict__ zh, const int* __restrict__ assign,
    _Float16* __restrict__ ph, float* __restrict__ pnorm)   // pnorm zero-init
{
    const int c = blockIdx.y;
    const int d = blockIdx.x * 256 + threadIdx.x;
    __shared__ int sa_[N_SUP];
    if (threadIdx.x < N_SUP) sa_[threadIdx.x] = assign[c * N_SUP + threadIdx.x];
    __syncthreads();
    int cnt1 = 0;
#pragma unroll
    for (int s = 0; s < N_SUP; ++s) cnt1 += sa_[s];
    const int cnt0 = N_SUP - cnt1;

    const _Float16* zc = zh + (size_t)c * N_SUP * Z_DIM;
    float s0 = 0.f, s1 = 0.f;
#pragma unroll
    for (int s = 0; s < N_SUP; ++s) {
        float v = (float)zc[(size_t)s * Z_DIM + d];
        if (sa_[s]) s1 += v; else s0 += v;
    }
    float c0 = (cnt0 > 0) ? (s0 / (float)cnt0) : (float)zc[d];
    float c1 = (cnt1 > 0) ? (s1 / (float)cnt1) : (float)zc[Z_DIM + d];
    ph[(size_t)(2 * c)     * Z_DIM + d] = (_Float16)c0;
    ph[(size_t)(2 * c + 1) * Z_DIM + d] = (_Float16)c1;

    float n0 = c0 * c0, n1 = c1 * c1;
    for (int off = 32; off; off >>= 1) {
        n0 += __shfl_down(n0, off);
        n1 += __shfl_down(n1, off);
    }
    if ((threadIdx.x & 63) == 0) {
        atomicAdd(&pnorm[2 * c],     n0);
        atomicAdd(&pnorm[2 * c + 1], n1);
    }
}

// ---- fused dist + per-query reduce: block = 32 queries x all 256 protos ------
// S = zq @ protos^T via f16 MFMA; d = min_k max(qn+pn-2S, 0) -> LDS;
// per-row sum/argmax/own-log -> one float2 partial per block.
#define TBM 32
#define TBN 256
#define TBK 32
__global__ __launch_bounds__(256) void distred_kernel(
    const _Float16* __restrict__ zqh,   // 16384 x 1024
    const _Float16* __restrict__ ph,    // 256 x 1024 (N x K)
    const float* __restrict__ pnorm, const float* __restrict__ qnorm,
    float2* __restrict__ partial)       // 512
{
    __shared__ _Float16 sA[TBM * TBK];     //  2 KB
    __shared__ _Float16 sB[TBN * TBK];     // 16 KB
    __shared__ float sD[TBM][N_CLASS + 1]; // 16.1 KB (pad breaks write conflicts)
    __shared__ float swl[4], swa[4];
    const int tid  = threadIdx.x;
    const int lane = tid & 63;
    const int wave = tid >> 6;
    const int q0   = blockIdx.x * TBM;
    const int wn   = wave * 64;            // each wave: all 32 rows x 64 cols

    // staging: A = 128 chunks of 16B (threads 0..127); B = 1024 chunks (4/thread)
    const _Float16* ga = zqh + (size_t)(q0 + (tid >> 2)) * Z_DIM + ((tid & 3) << 3);
    _Float16* la = &sA[tid * 8];
    const _Float16* gb[4]; _Float16* lb[4];
#pragma unroll
    for (int i = 0; i < 4; ++i) {
        const int f = tid + 256 * i;
        gb[i] = ph + (size_t)(f >> 2) * Z_DIM + ((f & 3) << 3);
        lb[i] = &sB[f * 8];
    }

    f32x4 acc[2][4];
#pragma unroll
    for (int i = 0; i < 2; ++i)
#pragma unroll
        for (int j = 0; j < 4; ++j) acc[i][j] = (f32x4){0.f, 0.f, 0.f, 0.f};

    const int rf = lane & 15;
    const int ko = (lane >> 4) * 8;

    for (int k0 = 0; k0 < Z_DIM; k0 += TBK) {
        if (tid < 128) load_lds16(ga + k0, la);
#pragma unroll
        for (int i = 0; i < 4; ++i) load_lds16(gb[i] + k0, lb[i]);
        __syncthreads();
        f16x8 af[2], bfr[4];
#pragma unroll
        for (int i = 0; i < 2; ++i)
            af[i] = *(const f16x8*)&sA[(i * 16 + rf) * TBK + ko];
#pragma unroll
        for (int j = 0; j < 4; ++j)
            bfr[j] = *(const f16x8*)&sB[(wn + j * 16 + rf) * TBK + ko];
#pragma unroll
        for (int i = 0; i < 2; ++i)
#pragma unroll
            for (int j = 0; j < 4; ++j)
                acc[i][j] = __builtin_amdgcn_mfma_f32_16x16x32_f16(
                    af[i], bfr[j], acc[i][j], 0, 0, 0);
        __syncthreads();
    }

    // epilogue 1: dists into LDS (pair-min over K=2)
    float pn[4];
#pragma unroll
    for (int j = 0; j < 4; ++j) pn[j] = pnorm[wn + j * 16 + rf];
#pragma unroll
    for (int i = 0; i < 2; ++i) {
#pragma unroll
        for (int r = 0; r < 4; ++r) {
            const int row = i * 16 + (lane >> 4) * 4 + r;
            const float qn = qnorm[q0 + row];
#pragma unroll
            for (int j = 0; j < 4; ++j) {
                float d = fmaxf(qn + pn[j] - 2.f * acc[i][j][r], 0.f);
                float o = __shfl_xor(d, 1);
                if (!(lane & 1))
                    sD[row][(wn >> 1) + j * 8 + (rf >> 1)] = fminf(d, o);
            }
        }
    }
    __syncthreads();

    // epilogue 2: per-row sum/argmax/own; 8 rows per wave
    float L = 0.f, A = 0.f;
#pragma unroll
    for (int rr = 0; rr < 8; ++rr) {
        const int row = wave * 8 + rr;
        const float va = sD[row][lane];
        const float vb = sD[row][lane + 64];
        float sum = va + vb;
        float bv; int bi;
        if (vb > va) { bv = vb; bi = lane + 64; } else { bv = va; bi = lane; }
        for (int off = 32; off; off >>= 1) {
            sum += __shfl_down(sum, off);
            float ov = __shfl_down(bv, off);
            int   oi = __shfl_down(bi, off);
            if (ov > bv || (ov == bv && oi < bi)) { bv = ov; bi = oi; }
        }
        if (lane == 0) {
            const int c = (q0 + row) >> 7;
            L += logf(sD[row][c] / sum);
            A += (bi == c) ? 1.f : 0.f;
        }
    }
    if (lane == 0) { swl[wave] = L; swa[wave] = A; }
    __syncthreads();
    if (tid == 0)
        partial[blockIdx.x] = make_float2(swl[0] + swl[1] + swl[2] + swl[3],
                                          swa[0] + swa[1] + swa[2] + swa[3]);
}

// ---------------- final reduce over 512 partials (single block) ---------------
__global__ __launch_bounds__(512) void finalize_kernel(
    const float2* __restrict__ partial, float* __restrict__ out)
{
    __shared__ float sl[8], sa[8];
    const int tid = threadIdx.x;
    float2 p = partial[tid];
    float l = p.x, a = p.y;
    for (int off = 32; off; off >>= 1) {
        l += __shfl_down(l, off);
        a += __shfl_down(a, off);
    }
    const int lane = tid & 63, wave = tid >> 6;
    if (lane == 0) { sl[wave] = l; sa[wave] = a; }
    __syncthreads();
    if (tid == 0) {
        float L = 0.f, A = 0.f;
#pragma unroll
        for (int w = 0; w < 8; ++w) { L += sl[w]; A += sa[w]; }
        out[0] = -L / (float)N_Q;
        out[1] =  A / (float)N_Q;
    }
}

// ---------------- launch ----------------
extern "C" void kernel_launch(void* const* d_in, const int* in_sizes, int n_in,
                              void* d_out, int out_size, void* d_ws, size_t ws_size,
                              hipStream_t stream)
{
    (void)in_sizes; (void)n_in; (void)out_size; (void)ws_size;
    const float* xs = (const float*)d_in[0];
    const float* xq = (const float*)d_in[1];
    const float* W  = (const float*)d_in[2];
    float* out = (float*)d_out;

    char* ws = (char*)d_ws;
    _Float16*       zh     = (_Float16*)(ws);                     //  41,943,040 B
    unsigned short* xb     = (unsigned short*)(ws + 41943040ull); //  83,886,080 B
    unsigned short* wt     = (unsigned short*)(ws + 125829120ull);//   4,194,304 B
    _Float16*       ph     = (_Float16*)(ws + 130023424ull);      //     524,288 B
    float*          pnorm  = (float*)(ws + 130547712ull);         //       1,024 B
    float*          qnorm  = (float*)(ws + 130548736ull);         //      65,536 B
    float2*         partial= (float2*)(ws + 130614272ull);        //       4,096 B
    int*            assign = (int*)(ws + 130618368ull);           //      16,384 B

    cast_all<<<N_ROWS * D_IN / 1024, 256, 0, stream>>>(xs, xq, xb);
    wt_kernel<<<dim3(Z_DIM / 64, D_IN / 64), 256, 0, stream>>>(W, wt);
    hipMemsetAsync(pnorm, 0, 1024 + N_Q * sizeof(float), stream);  // pnorm+qnorm

    dim3 gA(Z_DIM / GBN, N_ROWS / GBM);   // (8, 160) -> swizzled in-kernel
    gemm_mfma<<<gA, 256, 0, stream>>>(xb, wt, zh, qnorm);

    assign_kernel<<<N_S / 4, 256, 0, stream>>>(zh, assign);
    centroid_kernel<<<dim3(Z_DIM / 256, N_CLASS), 256, 0, stream>>>(zh, assign, ph, pnorm);

    const _Float16* zqh = zh + (size_t)N_S * Z_DIM;
    distred_kernel<<<N_Q / TBM, 256, 0, stream>>>(zqh, ph, pnorm, qnorm, partial);

    finalize_kernel<<<1, 512, 0, stream>>>(partial, out);
}